// Round 7
// baseline (1836.136 us; speedup 1.0000x reference)
//
#include <hip/hip_runtime.h>
#include <cstdint>

#define Bb 8
#define Nn 2048
#define Kk 20
#define FC 512
#define EPSc 1e-5f
#define SLOPEc 0.2f

#define TS 128
#define KP 32
#define LDT2 36

typedef __attribute__((ext_vector_type(8))) short short8v;
typedef __attribute__((ext_vector_type(4))) float f32x4;

static __device__ __forceinline__ float leaky(float y){ return y >= 0.f ? y : SLOPEc * y; }

static __device__ __forceinline__ ushort f2bf(float x){
  uint u = __float_as_uint(x);
  return (ushort)((u + 0x7fffu + ((u >> 16) & 1u)) >> 16);
}
static __device__ __forceinline__ float bf2f(ushort b){
  return __uint_as_float(((uint)b) << 16);
}

// ---------------- Wt prep: Wt1[c][o] = W[o][c]; Wt2[c][o] = W[o][C+c]-W[o][c]
__global__ void wt_prep_k(const float* __restrict__ W, float* __restrict__ Wt1,
                          float* __restrict__ Wt2, int C, int O){
  int i = blockIdx.x * 256 + threadIdx.x;
  if(i >= C * O) return;
  int c = i / O, o = i - c * O;
  float w1 = W[o * 2 * C + c];
  float w2 = W[o * 2 * C + C + c];
  Wt1[c * O + o] = w1;
  Wt2[c * O + o] = w2 - w1;
}

// ---------------- A = h·W1^T ; Bc = h·(W2-W1)^T   (16 rows per block)
template<int C, int O>
__global__ __launch_bounds__(256) void gemm_ab_k(const float* __restrict__ h, int hstride,
                    const float* __restrict__ Wt1, const float* __restrict__ Wt2,
                    float* __restrict__ A, float* __restrict__ Bc){
  constexpr int NG = 256 / O;
  constexpr int ROWS = 16;
  constexpr int RPG = ROWS / NG;
  __shared__ float xs[ROWS][C];
  int t = threadIdx.x;
  int row0 = blockIdx.x * ROWS;
  for(int i = t; i < ROWS * C; i += 256){
    int r = i / C, c = i - r * C;
    xs[r][c] = h[(size_t)(row0 + r) * hstride + c];
  }
  __syncthreads();
  int o = t % O, g = t / O;
  float accA[RPG], accB[RPG];
  #pragma unroll
  for(int r = 0; r < RPG; r++){ accA[r] = 0.f; accB[r] = 0.f; }
  for(int c = 0; c < C; c++){
    float wa = Wt1[c * O + o], wb = Wt2[c * O + o];
    #pragma unroll
    for(int r = 0; r < RPG; r++){
      float x = xs[g * RPG + r][c];
      accA[r] = fmaf(x, wa, accA[r]);
      accB[r] = fmaf(x, wb, accB[r]);
    }
  }
  for(int r = 0; r < RPG; r++){
    size_t id = (size_t)(row0 + g * RPG + r) * O + o;
    A[id] = accA[r];
    Bc[id] = accB[r];
  }
}

// ---------------- gather + k-reduce (max/min) + DETERMINISTIC BN partials
// (atomicAdd removed: float atomics are order-nondeterministic across calls,
//  which re-rolls near-tie kNN neighbors every replay -> post-timing divergence)
template<int O>
__global__ __launch_bounds__(256) void edge_reduce_k(const float* __restrict__ A,
                       const float* __restrict__ Bc, const int* __restrict__ idx,
                       float* __restrict__ outMax, float* __restrict__ outMin,
                       float* __restrict__ psum, float* __restrict__ psq){
  constexpr int NG = 256 / O;
  constexpr int RPG = 16;
  constexpr int ROWS = NG * RPG;
  int t = threadIdx.x;
  int o = t % O, g = t / O;
  int blocks_per_b = Nn / ROWS;
  int b = blockIdx.x / blocks_per_b;
  int n0 = (blockIdx.x % blocks_per_b) * ROWS;
  float tsum = 0.f, tsq = 0.f;
  for(int r = 0; r < RPG; r++){
    int n = n0 + g * RPG + r;
    size_t rowid = (size_t)b * Nn + n;
    const int* ip = idx + rowid * Kk;
    float bv = Bc[rowid * O + o];
    float amax = -3.4e38f, amin = 3.4e38f, asum = 0.f, asq = 0.f;
    for(int k = 0; k < Kk; k++){
      int nb = ip[k];
      float a = A[((size_t)b * Nn + nb) * O + o];
      amax = fmaxf(amax, a);
      amin = fminf(amin, a);
      asum += a;
      asq = fmaf(a, a, asq);
    }
    outMax[rowid * FC + o] = amax + bv;
    outMin[rowid * O + o]  = amin + bv;
    tsum += asum + (float)Kk * bv;
    tsq  += asq + 2.f * bv * asum + (float)Kk * bv * bv;
  }
  __shared__ float red[256];
  red[t] = tsum; __syncthreads();
  if(g == 0){
    float s = 0.f;
    for(int gg = 0; gg < NG; gg++) s += red[gg * O + o];
    psum[(size_t)blockIdx.x * O + o] = s;
  }
  __syncthreads();
  red[t] = tsq; __syncthreads();
  if(g == 0){
    float s = 0.f;
    for(int gg = 0; gg < NG; gg++) s += red[gg * O + o];
    psq[(size_t)blockIdx.x * O + o] = s;
  }
}

// ---------------- deterministic BN finalize: one wave per channel,
// fixed strided partial-sum order + fixed shfl butterfly
__global__ __launch_bounds__(64) void bn_finalize2_k(const float* __restrict__ psum,
                              const float* __restrict__ psq,
                              const float* __restrict__ gam, const float* __restrict__ bet,
                              float* __restrict__ scale, float* __restrict__ shift,
                              int O, int nb){
  int o = blockIdx.x;
  int t = threadIdx.x;
  float s = 0.f, q = 0.f;
  for(int bk = t; bk < nb; bk += 64){
    s += psum[(size_t)bk * O + o];
    q += psq[(size_t)bk * O + o];
  }
  #pragma unroll
  for(int off2 = 1; off2 < 64; off2 <<= 1){
    s += __shfl_xor(s, off2, 64);
    q += __shfl_xor(q, off2, 64);
  }
  if(t == 0){
    float cnt = (float)Bb * (float)Nn * (float)Kk;
    float mean = s / cnt;
    float var = q / cnt - mean * mean;
    var = fmaxf(var, 0.f);
    float sc = gam[o] * rsqrtf(var + EPSc);
    scale[o] = sc;
    shift[o] = bet[o] - mean * sc;
  }
}

__global__ void bn_apply_k(float* __restrict__ featsl, const float* __restrict__ Mn,
                           const float* __restrict__ scale, const float* __restrict__ shift,
                           const float* __restrict__ gam, int O){
  int i = blockIdx.x * 256 + threadIdx.x;
  if(i >= Bb * Nn * O) return;
  int o = i % O;
  size_t row = (size_t)(i / O);
  float v = (gam[o] >= 0.f) ? featsl[row * FC + o] : Mn[row * O + o];
  float y = fmaf(scale[o], v, shift[o]);
  featsl[row * FC + o] = leaky(y);
}

// ---------------- row squared norms
__global__ void rownorm_k(const float* __restrict__ featsl, float* __restrict__ xx, int C){
  int i = blockIdx.x * 256 + threadIdx.x;
  if(i >= Bb * Nn) return;
  const float* p = featsl + (size_t)i * FC;
  float s = 0.f;
  for(int c = 0; c < C; c++) s = fmaf(p[c], p[c], s);
  xx[i] = s;
}

// ---------------- neg_dist 128x128-tile GEMM (8x8 micro), b128 LDS reads.
// __launch_bounds__(256,4): VGPR budget 128 so the 64-deep f32 accumulator
// stays in VGPRs (at 84 regs the compiler sinks acc to AGPRs -> 3 VALU/FMA).
template<int CIN>
__global__ __launch_bounds__(256, 4) void gram2_k(const float* __restrict__ feat,
                     const float* __restrict__ xx, float* __restrict__ nd, int b0){
  int b = b0 + blockIdx.z;
  float* ndb = nd + (size_t)blockIdx.z * Nn * Nn;
  int n0 = blockIdx.y * TS, m0 = blockIdx.x * TS;
  __shared__ float fa[TS * LDT2];
  __shared__ float fb[TS * LDT2];
  int t = threadIdx.x, tx = t & 15, ty = t >> 4;
  float acc[8][8] = {};
  const float* Abase = feat + ((size_t)b * Nn + n0) * FC;
  const float* Bbase = feat + ((size_t)b * Nn + m0) * FC;
  for(int c0 = 0; c0 < CIN; c0 += KP){
    #pragma unroll
    for(int p = 0; p < 4; p++){
      int f = t + p * 256;
      int n = f >> 3, c4 = (f & 7) << 2;
      float4 va = *(const float4*)(Abase + (size_t)n * FC + c0 + c4);
      float4 vb = *(const float4*)(Bbase + (size_t)n * FC + c0 + c4);
      *(float4*)&fa[n * LDT2 + c4] = va;
      *(float4*)&fb[n * LDT2 + c4] = vb;
    }
    __syncthreads();
    #pragma unroll
    for(int c4 = 0; c4 < KP; c4 += 4){
      float4 a4[8];
      #pragma unroll
      for(int i = 0; i < 8; i++) a4[i] = *(const float4*)&fa[(ty + 16 * i) * LDT2 + c4];
      #pragma unroll
      for(int j = 0; j < 8; j++){
        float4 b4 = *(const float4*)&fb[(tx + 16 * j) * LDT2 + c4];
        #pragma unroll
        for(int i = 0; i < 8; i++) acc[i][j] = fmaf(a4[i].x, b4.x, acc[i][j]);
        #pragma unroll
        for(int i = 0; i < 8; i++) acc[i][j] = fmaf(a4[i].y, b4.y, acc[i][j]);
        #pragma unroll
        for(int i = 0; i < 8; i++) acc[i][j] = fmaf(a4[i].z, b4.z, acc[i][j]);
        #pragma unroll
        for(int i = 0; i < 8; i++) acc[i][j] = fmaf(a4[i].w, b4.w, acc[i][j]);
      }
    }
    __syncthreads();
  }
  float xn[8], xm[8];
  #pragma unroll
  for(int i = 0; i < 8; i++) xn[i] = xx[(size_t)b * Nn + n0 + ty + 16 * i];
  #pragma unroll
  for(int j = 0; j < 8; j++) xm[j] = xx[(size_t)b * Nn + m0 + tx + 16 * j];
  #pragma unroll
  for(int i = 0; i < 8; i++){
    size_t rbase = (size_t)(n0 + ty + 16 * i) * Nn + m0;
    #pragma unroll
    for(int j = 0; j < 8; j++)
      ndb[rbase + tx + 16 * j] = 2.f * acc[i][j] - xn[i] - xm[j];
  }
}

// ---------------- wave-per-row top-K (no barriers, registers only)
__global__ __launch_bounds__(256) void topk_w(const float* __restrict__ nd,
                                              int* __restrict__ idxout, int rowbase){
  int wid = threadIdx.x >> 6, lane = threadIdx.x & 63;
  int row = blockIdx.x * 4 + wid;
  const float* src = nd + (size_t)row * Nn;
  float x[32];
  #pragma unroll
  for(int j = 0; j < 32; j++) x[j] = src[j * 64 + lane];
  int sel = 0;
  for(int s = 0; s < Kk; s++){
    float m = x[0];
    #pragma unroll
    for(int j = 1; j < 32; j++) m = fmaxf(m, x[j]);
    #pragma unroll
    for(int off = 1; off < 64; off <<= 1) m = fmaxf(m, __shfl_xor(m, off, 64));
    int bi = 0x7fffffff;
    #pragma unroll
    for(int j = 31; j >= 0; j--) bi = (x[j] == m) ? (j * 64 + lane) : bi;
    #pragma unroll
    for(int off = 1; off < 64; off <<= 1){ int ob = __shfl_xor(bi, off, 64); bi = min(bi, ob); }
    if(lane == s) sel = bi;
    #pragma unroll
    for(int j = 0; j < 32; j++) x[j] = (bi == j * 64 + lane) ? -3.4e38f : x[j];
  }
  if(lane < Kk) idxout[((size_t)(rowbase + row)) * Kk + lane] = sel;
}

// ---------------- f32 -> (hi,lo) bf16 split
__global__ void cvt_k(const float* __restrict__ in, ushort* __restrict__ hi,
                      ushort* __restrict__ lo, int n4){
  int i = blockIdx.x * 256 + threadIdx.x;
  if(i >= n4) return;
  float4 v = *(const float4*)(in + (size_t)i * 4);
  float vv[4] = {v.x, v.y, v.z, v.w};
  ushort h[4], l[4];
  #pragma unroll
  for(int j = 0; j < 4; j++){
    h[j] = f2bf(vv[j]);
    float r = vv[j] - bf2f(h[j]);
    l[j] = f2bf(r);
  }
  ushort4 uh, ul;
  uh.x = h[0]; uh.y = h[1]; uh.z = h[2]; uh.w = h[3];
  ul.x = l[0]; ul.y = l[1]; ul.z = l[2]; ul.w = l[3];
  ((ushort4*)hi)[i] = uh;
  ((ushort4*)lo)[i] = ul;
}

// ---------------- final conv via split-bf16 MFMA + fused col-max
#define LDH 40
__global__ __launch_bounds__(256) void fc3_k(const ushort* __restrict__ fH, const ushort* __restrict__ fL,
        const ushort* __restrict__ wH, const ushort* __restrict__ wL,
        float* __restrict__ pmax){
  __shared__ ushort aH[128 * LDH], aL[128 * LDH], bH[128 * LDH], bL[128 * LDH];
  __shared__ float red[2][128];
  int t = threadIdx.x;
  int lane = t & 63, wid = t >> 6;
  int wm = wid >> 1, wn = wid & 1;
  int rt = blockIdx.y, o0 = blockIdx.x * 128;
  const ushort* gaH = fH + (size_t)rt * 128 * 512;
  const ushort* gaL = fL + (size_t)rt * 128 * 512;
  const ushort* gbH = wH + (size_t)o0 * 512;
  const ushort* gbL = wL + (size_t)o0 * 512;
  f32x4 acc[4][4];
  #pragma unroll
  for(int i = 0; i < 4; i++)
    #pragma unroll
    for(int j = 0; j < 4; j++)
      acc[i][j] = (f32x4){0.f, 0.f, 0.f, 0.f};
  for(int c0 = 0; c0 < 512; c0 += 32){
    #pragma unroll
    for(int p = 0; p < 2; p++){
      int r = (t >> 2) + p * 64, s = (t & 3) * 8;
      size_t go = (size_t)r * 512 + c0 + s;
      int lof = r * LDH + s;
      *(uint4*)&aH[lof] = *(const uint4*)&gaH[go];
      *(uint4*)&aL[lof] = *(const uint4*)&gaL[go];
      *(uint4*)&bH[lof] = *(const uint4*)&gbH[go];
      *(uint4*)&bL[lof] = *(const uint4*)&gbL[go];
    }
    __syncthreads();
    int koff = (lane >> 4) * 8;
    short8v AH[4], AL[4], BH[4], BL[4];
    #pragma unroll
    for(int f = 0; f < 4; f++){
      int ra = (wm * 64 + f * 16 + (lane & 15)) * LDH + koff;
      AH[f] = *(const short8v*)&aH[ra];
      AL[f] = *(const short8v*)&aL[ra];
      int rb = (wn * 64 + f * 16 + (lane & 15)) * LDH + koff;
      BH[f] = *(const short8v*)&bH[rb];
      BL[f] = *(const short8v*)&bL[rb];
    }
    #pragma unroll
    for(int i = 0; i < 4; i++)
      #pragma unroll
      for(int j = 0; j < 4; j++){
        acc[i][j] = __builtin_amdgcn_mfma_f32_16x16x32_bf16(AH[i], BH[j], acc[i][j], 0, 0, 0);
        acc[i][j] = __builtin_amdgcn_mfma_f32_16x16x32_bf16(AH[i], BL[j], acc[i][j], 0, 0, 0);
        acc[i][j] = __builtin_amdgcn_mfma_f32_16x16x32_bf16(AL[i], BH[j], acc[i][j], 0, 0, 0);
      }
    __syncthreads();
  }
  #pragma unroll
  for(int j = 0; j < 4; j++){
    float m = -3.4e38f;
    #pragma unroll
    for(int i = 0; i < 4; i++)
      m = fmaxf(m, fmaxf(fmaxf(acc[i][j][0], acc[i][j][1]), fmaxf(acc[i][j][2], acc[i][j][3])));
    m = fmaxf(m, __shfl_xor(m, 16, 64));
    m = fmaxf(m, __shfl_xor(m, 32, 64));
    if(lane < 16) red[wm][wn * 64 + j * 16 + lane] = m;
  }
  __syncthreads();
  if(t < 128)
    pmax[(size_t)rt * 1024 + o0 + t] = fmaxf(red[0][t], red[1][t]);
}

__global__ void fc_reduce_k(const float* __restrict__ pmax, const float* __restrict__ bf,
                            float* __restrict__ out){
  int i = blockIdx.x * 256 + threadIdx.x;
  if(i >= Bb * 1024) return;
  int b = i >> 10, o = i & 1023;
  float m = -3.4e38f;
  for(int rt = b * 16; rt < b * 16 + 16; rt++) m = fmaxf(m, pmax[(size_t)rt * 1024 + o]);
  out[i] = m + bf[o];
}

// =====================================================================
extern "C" void kernel_launch(void* const* d_in, const int* in_sizes, int n_in,
                              void* d_out, int out_size, void* d_ws, size_t ws_size,
                              hipStream_t stream){
  const float* x  = (const float*)d_in[0];
  const int* idx0 = (const int*)d_in[1];
  const float* Wl[4] = {(const float*)d_in[2], (const float*)d_in[5], (const float*)d_in[8],  (const float*)d_in[11]};
  const float* Gl[4] = {(const float*)d_in[3], (const float*)d_in[6], (const float*)d_in[9],  (const float*)d_in[12]};
  const float* Bl[4] = {(const float*)d_in[4], (const float*)d_in[7], (const float*)d_in[10], (const float*)d_in[13]};
  const float* wf = (const float*)d_in[14];
  const float* bf = (const float*)d_in[15];
  float* out = (float*)d_out;

  char* base = (char*)d_ws;
  size_t off = 0;
  auto alloc = [&](size_t bytes) -> char* {
    char* p = base + off;
    off += (bytes + 255) & ~(size_t)255;
    return p;
  };
  float* feat = (float*)alloc((size_t)Bb * Nn * FC * 4);
  float* Abuf = (float*)alloc((size_t)Bb * Nn * 256 * 4);
  float* Bbuf = (float*)alloc((size_t)Bb * Nn * 256 * 4);
  float* Mn   = (float*)alloc((size_t)Bb * Nn * 256 * 4);
  int*   idxb = (int*)  alloc((size_t)Bb * Nn * Kk * 4);
  float* xx   = (float*)alloc((size_t)Bb * Nn * 4);
  float* Wt1  = (float*)alloc(128 * 256 * 4);
  float* Wt2  = (float*)alloc(128 * 256 * 4);
  float* psum = (float*)alloc((size_t)1024 * 256 * 4);
  float* psq  = (float*)alloc((size_t)1024 * 256 * 4);
  float* scal = (float*)alloc(256 * 4);
  float* shft = (float*)alloc(256 * 4);
  float* pmax = (float*)alloc((size_t)128 * 1024 * 4);
  float* nd   = (float*)(base + off);
  bool fullND = (off + (size_t)Bb * Nn * Nn * 4) <= ws_size;

  ushort* featH = (ushort*)Abuf;
  ushort* featL = (ushort*)Bbuf;
  ushort* wfH   = (ushort*)Mn;
  ushort* wfL   = ((ushort*)Mn) + (size_t)1024 * 512;

  // ---------------- Layer 0 (given indices, C=3, O=64, out at feat+0)
  wt_prep_k<<<(3 * 64 + 255) / 256, 256, 0, stream>>>(Wl[0], Wt1, Wt2, 3, 64);
  gemm_ab_k<3, 64><<<Bb * Nn / 16, 256, 0, stream>>>(x, 3, Wt1, Wt2, Abuf, Bbuf);
  edge_reduce_k<64><<<Bb * Nn / 64, 256, 0, stream>>>(Abuf, Bbuf, idx0, feat + 0, Mn, psum, psq);
  bn_finalize2_k<<<64, 64, 0, stream>>>(psum, psq, Gl[0], Bl[0], scal, shft, 64, Bb * Nn / 64);
  bn_apply_k<<<(Bb * Nn * 64) / 256, 256, 0, stream>>>(feat + 0, Mn, scal, shft, Gl[0], 64);

  #define RUN_KNN(CIN, OFFIN)                                                            \
    rownorm_k<<<Bb * Nn / 256, 256, 0, stream>>>(feat + (OFFIN), xx, (CIN));             \
    if(fullND){                                                                          \
      gram2_k<CIN><<<dim3(16, 16, 8), 256, 0, stream>>>(feat + (OFFIN), xx, nd, 0);      \
      topk_w<<<Bb * Nn / 4, 256, 0, stream>>>(nd, idxb, 0);                              \
    } else {                                                                             \
      for(int bb = 0; bb < Bb; bb++){                                                    \
        gram2_k<CIN><<<dim3(16, 16, 1), 256, 0, stream>>>(feat + (OFFIN), xx, nd, bb);   \
        topk_w<<<Nn / 4, 256, 0, stream>>>(nd, idxb, bb * Nn);                           \
      }                                                                                  \
    }

  // ---------------- Layer 1
  RUN_KNN(64, 0)
  wt_prep_k<<<(64 * 64 + 255) / 256, 256, 0, stream>>>(Wl[1], Wt1, Wt2, 64, 64);
  gemm_ab_k<64, 64><<<Bb * Nn / 16, 256, 0, stream>>>(feat + 0, FC, Wt1, Wt2, Abuf, Bbuf);
  edge_reduce_k<64><<<Bb * Nn / 64, 256, 0, stream>>>(Abuf, Bbuf, idxb, feat + 64, Mn, psum, psq);
  bn_finalize2_k<<<64, 64, 0, stream>>>(psum, psq, Gl[1], Bl[1], scal, shft, 64, Bb * Nn / 64);
  bn_apply_k<<<(Bb * Nn * 64) / 256, 256, 0, stream>>>(feat + 64, Mn, scal, shft, Gl[1], 64);

  // ---------------- Layer 2
  RUN_KNN(64, 64)
  wt_prep_k<<<(64 * 128 + 255) / 256, 256, 0, stream>>>(Wl[2], Wt1, Wt2, 64, 128);
  gemm_ab_k<64, 128><<<Bb * Nn / 16, 256, 0, stream>>>(feat + 64, FC, Wt1, Wt2, Abuf, Bbuf);
  edge_reduce_k<128><<<Bb * Nn / 32, 256, 0, stream>>>(Abuf, Bbuf, idxb, feat + 128, Mn, psum, psq);
  bn_finalize2_k<<<128, 64, 0, stream>>>(psum, psq, Gl[2], Bl[2], scal, shft, 128, Bb * Nn / 32);
  bn_apply_k<<<(Bb * Nn * 128) / 256, 256, 0, stream>>>(feat + 128, Mn, scal, shft, Gl[2], 128);

  // ---------------- Layer 3
  RUN_KNN(128, 128)
  wt_prep_k<<<(128 * 256 + 255) / 256, 256, 0, stream>>>(Wl[3], Wt1, Wt2, 128, 256);
  gemm_ab_k<128, 256><<<Bb * Nn / 16, 256, 0, stream>>>(feat + 128, FC, Wt1, Wt2, Abuf, Bbuf);
  edge_reduce_k<256><<<Bb * Nn / 16, 256, 0, stream>>>(Abuf, Bbuf, idxb, feat + 256, Mn, psum, psq);
  bn_finalize2_k<<<256, 64, 0, stream>>>(psum, psq, Gl[3], Bl[3], scal, shft, 256, Bb * Nn / 16);
  bn_apply_k<<<(Bb * Nn * 256) / 256, 256, 0, stream>>>(feat + 256, Mn, scal, shft, Gl[3], 256);

  // ---------------- Final 1x1 conv (split-bf16 MFMA) + global max pool
  cvt_k<<<(Bb * Nn * FC / 4 + 255) / 256, 256, 0, stream>>>(feat, featH, featL, Bb * Nn * FC / 4);
  cvt_k<<<(1024 * 512 / 4 + 255) / 256, 256, 0, stream>>>(wf, wfH, wfL, 1024 * 512 / 4);
  fc3_k<<<dim3(8, 128), 256, 0, stream>>>(featH, featL, wfH, wfL, pmax);
  fc_reduce_k<<<(Bb * 1024 + 255) / 256, 256, 0, stream>>>(pmax, bf, out);
  #undef RUN_KNN
}

// Round 8
// 868.060 us; speedup vs baseline: 2.1152x; 2.1152x over previous
//
#include <hip/hip_runtime.h>
#include <cstdint>

#define Bb 8
#define Nn 2048
#define Kk 20
#define FC 512
#define EPSc 1e-5f
#define SLOPEc 0.2f

#define TS 128
#define KP 32
#define LDT2 36

typedef __attribute__((ext_vector_type(8))) short short8v;
typedef __attribute__((ext_vector_type(4))) float f32x4;

static __device__ __forceinline__ float leaky(float y){ return y >= 0.f ? y : SLOPEc * y; }

static __device__ __forceinline__ ushort f2bf(float x){
  uint u = __float_as_uint(x);
  return (ushort)((u + 0x7fffu + ((u >> 16) & 1u)) >> 16);
}
static __device__ __forceinline__ float bf2f(ushort b){
  return __uint_as_float(((uint)b) << 16);
}

// ---------------- Wt prep: Wt1[c][o] = W[o][c]; Wt2[c][o] = W[o][C+c]-W[o][c]
__global__ void wt_prep_k(const float* __restrict__ W, float* __restrict__ Wt1,
                          float* __restrict__ Wt2, int C, int O){
  int i = blockIdx.x * 256 + threadIdx.x;
  if(i >= C * O) return;
  int c = i / O, o = i - c * O;
  float w1 = W[o * 2 * C + c];
  float w2 = W[o * 2 * C + C + c];
  Wt1[c * O + o] = w1;
  Wt2[c * O + o] = w2 - w1;
}

// ---------------- A = h·W1^T ; Bc = h·(W2-W1)^T   (16 rows per block)
template<int C, int O>
__global__ __launch_bounds__(256) void gemm_ab_k(const float* __restrict__ h, int hstride,
                    const float* __restrict__ Wt1, const float* __restrict__ Wt2,
                    float* __restrict__ A, float* __restrict__ Bc){
  constexpr int NG = 256 / O;
  constexpr int ROWS = 16;
  constexpr int RPG = ROWS / NG;
  __shared__ float xs[ROWS][C];
  int t = threadIdx.x;
  int row0 = blockIdx.x * ROWS;
  for(int i = t; i < ROWS * C; i += 256){
    int r = i / C, c = i - r * C;
    xs[r][c] = h[(size_t)(row0 + r) * hstride + c];
  }
  __syncthreads();
  int o = t % O, g = t / O;
  float accA[RPG], accB[RPG];
  #pragma unroll
  for(int r = 0; r < RPG; r++){ accA[r] = 0.f; accB[r] = 0.f; }
  for(int c = 0; c < C; c++){
    float wa = Wt1[c * O + o], wb = Wt2[c * O + o];
    #pragma unroll
    for(int r = 0; r < RPG; r++){
      float x = xs[g * RPG + r][c];
      accA[r] = fmaf(x, wa, accA[r]);
      accB[r] = fmaf(x, wb, accB[r]);
    }
  }
  for(int r = 0; r < RPG; r++){
    size_t id = (size_t)(row0 + g * RPG + r) * O + o;
    A[id] = accA[r];
    Bc[id] = accB[r];
  }
}

// ---------------- gather + k-reduce (max/min) + DETERMINISTIC BN partials
template<int O>
__global__ __launch_bounds__(256) void edge_reduce_k(const float* __restrict__ A,
                       const float* __restrict__ Bc, const int* __restrict__ idx,
                       float* __restrict__ outMax, float* __restrict__ outMin,
                       float* __restrict__ psum, float* __restrict__ psq){
  constexpr int NG = 256 / O;
  constexpr int RPG = 16;
  constexpr int ROWS = NG * RPG;
  int t = threadIdx.x;
  int o = t % O, g = t / O;
  int blocks_per_b = Nn / ROWS;
  int b = blockIdx.x / blocks_per_b;
  int n0 = (blockIdx.x % blocks_per_b) * ROWS;
  float tsum = 0.f, tsq = 0.f;
  for(int r = 0; r < RPG; r++){
    int n = n0 + g * RPG + r;
    size_t rowid = (size_t)b * Nn + n;
    const int* ip = idx + rowid * Kk;
    float bv = Bc[rowid * O + o];
    float amax = -3.4e38f, amin = 3.4e38f, asum = 0.f, asq = 0.f;
    for(int k = 0; k < Kk; k++){
      int nb = ip[k];
      float a = A[((size_t)b * Nn + nb) * O + o];
      amax = fmaxf(amax, a);
      amin = fminf(amin, a);
      asum += a;
      asq = fmaf(a, a, asq);
    }
    outMax[rowid * FC + o] = amax + bv;
    outMin[rowid * O + o]  = amin + bv;
    tsum += asum + (float)Kk * bv;
    tsq  += asq + 2.f * bv * asum + (float)Kk * bv * bv;
  }
  __shared__ float red[256];
  red[t] = tsum; __syncthreads();
  if(g == 0){
    float s = 0.f;
    for(int gg = 0; gg < NG; gg++) s += red[gg * O + o];
    psum[(size_t)blockIdx.x * O + o] = s;
  }
  __syncthreads();
  red[t] = tsq; __syncthreads();
  if(g == 0){
    float s = 0.f;
    for(int gg = 0; gg < NG; gg++) s += red[gg * O + o];
    psq[(size_t)blockIdx.x * O + o] = s;
  }
}

// ---------------- deterministic BN finalize: one wave per channel
__global__ __launch_bounds__(64) void bn_finalize2_k(const float* __restrict__ psum,
                              const float* __restrict__ psq,
                              const float* __restrict__ gam, const float* __restrict__ bet,
                              float* __restrict__ scale, float* __restrict__ shift,
                              int O, int nb){
  int o = blockIdx.x;
  int t = threadIdx.x;
  float s = 0.f, q = 0.f;
  for(int bk = t; bk < nb; bk += 64){
    s += psum[(size_t)bk * O + o];
    q += psq[(size_t)bk * O + o];
  }
  #pragma unroll
  for(int off2 = 1; off2 < 64; off2 <<= 1){
    s += __shfl_xor(s, off2, 64);
    q += __shfl_xor(q, off2, 64);
  }
  if(t == 0){
    float cnt = (float)Bb * (float)Nn * (float)Kk;
    float mean = s / cnt;
    float var = q / cnt - mean * mean;
    var = fmaxf(var, 0.f);
    float sc = gam[o] * rsqrtf(var + EPSc);
    scale[o] = sc;
    shift[o] = bet[o] - mean * sc;
  }
}

__global__ void bn_apply_k(float* __restrict__ featsl, const float* __restrict__ Mn,
                           const float* __restrict__ scale, const float* __restrict__ shift,
                           const float* __restrict__ gam, int O){
  int i = blockIdx.x * 256 + threadIdx.x;
  if(i >= Bb * Nn * O) return;
  int o = i % O;
  size_t row = (size_t)(i / O);
  float v = (gam[o] >= 0.f) ? featsl[row * FC + o] : Mn[row * O + o];
  float y = fmaf(scale[o], v, shift[o]);
  featsl[row * FC + o] = leaky(y);
}

// ---------------- row squared norms
__global__ void rownorm_k(const float* __restrict__ featsl, float* __restrict__ xx, int C){
  int i = blockIdx.x * 256 + threadIdx.x;
  if(i >= Bb * Nn) return;
  const float* p = featsl + (size_t)i * FC;
  float s = 0.f;
  for(int c = 0; c < C; c++) s = fmaf(p[c], p[c], s);
  xx[i] = s;
}

// ---------------- neg_dist 128x128-tile GEMM (8x8 micro), b128 LDS reads.
// __launch_bounds__(256,2): R7 showed hipcc maps (256,4) -> VGPR cap 64 and
// SPILLS the 64-deep accumulator to scratch (FETCH 33MB->838MB, 121->551us).
// (256,2) -> cap 128 >= ~115 live regs: no spill, no AGPR-sink. FMA DAG is
// unchanged from R7 -> nd bit-identical -> absmax stays 0.15625 (no re-roll).
template<int CIN>
__global__ __launch_bounds__(256, 2) void gram2_k(const float* __restrict__ feat,
                     const float* __restrict__ xx, float* __restrict__ nd, int b0){
  int b = b0 + blockIdx.z;
  float* ndb = nd + (size_t)blockIdx.z * Nn * Nn;
  int n0 = blockIdx.y * TS, m0 = blockIdx.x * TS;
  __shared__ float fa[TS * LDT2];
  __shared__ float fb[TS * LDT2];
  int t = threadIdx.x, tx = t & 15, ty = t >> 4;
  float acc[8][8] = {};
  const float* Abase = feat + ((size_t)b * Nn + n0) * FC;
  const float* Bbase = feat + ((size_t)b * Nn + m0) * FC;
  for(int c0 = 0; c0 < CIN; c0 += KP){
    #pragma unroll
    for(int p = 0; p < 4; p++){
      int f = t + p * 256;
      int n = f >> 3, c4 = (f & 7) << 2;
      float4 va = *(const float4*)(Abase + (size_t)n * FC + c0 + c4);
      float4 vb = *(const float4*)(Bbase + (size_t)n * FC + c0 + c4);
      *(float4*)&fa[n * LDT2 + c4] = va;
      *(float4*)&fb[n * LDT2 + c4] = vb;
    }
    __syncthreads();
    #pragma unroll
    for(int c4 = 0; c4 < KP; c4 += 4){
      float4 a4[8];
      #pragma unroll
      for(int i = 0; i < 8; i++) a4[i] = *(const float4*)&fa[(ty + 16 * i) * LDT2 + c4];
      #pragma unroll
      for(int j = 0; j < 8; j++){
        float4 b4 = *(const float4*)&fb[(tx + 16 * j) * LDT2 + c4];
        #pragma unroll
        for(int i = 0; i < 8; i++) acc[i][j] = fmaf(a4[i].x, b4.x, acc[i][j]);
        #pragma unroll
        for(int i = 0; i < 8; i++) acc[i][j] = fmaf(a4[i].y, b4.y, acc[i][j]);
        #pragma unroll
        for(int i = 0; i < 8; i++) acc[i][j] = fmaf(a4[i].z, b4.z, acc[i][j]);
        #pragma unroll
        for(int i = 0; i < 8; i++) acc[i][j] = fmaf(a4[i].w, b4.w, acc[i][j]);
      }
    }
    __syncthreads();
  }
  float xn[8], xm[8];
  #pragma unroll
  for(int i = 0; i < 8; i++) xn[i] = xx[(size_t)b * Nn + n0 + ty + 16 * i];
  #pragma unroll
  for(int j = 0; j < 8; j++) xm[j] = xx[(size_t)b * Nn + m0 + tx + 16 * j];
  #pragma unroll
  for(int i = 0; i < 8; i++){
    size_t rbase = (size_t)(n0 + ty + 16 * i) * Nn + m0;
    #pragma unroll
    for(int j = 0; j < 8; j++)
      ndb[rbase + tx + 16 * j] = 2.f * acc[i][j] - xn[i] - xm[j];
  }
}

// ---------------- wave-per-row top-K (no barriers, registers only)
__global__ __launch_bounds__(256) void topk_w(const float* __restrict__ nd,
                                              int* __restrict__ idxout, int rowbase){
  int wid = threadIdx.x >> 6, lane = threadIdx.x & 63;
  int row = blockIdx.x * 4 + wid;
  const float* src = nd + (size_t)row * Nn;
  float x[32];
  #pragma unroll
  for(int j = 0; j < 32; j++) x[j] = src[j * 64 + lane];
  int sel = 0;
  for(int s = 0; s < Kk; s++){
    float m = x[0];
    #pragma unroll
    for(int j = 1; j < 32; j++) m = fmaxf(m, x[j]);
    #pragma unroll
    for(int off = 1; off < 64; off <<= 1) m = fmaxf(m, __shfl_xor(m, off, 64));
    int bi = 0x7fffffff;
    #pragma unroll
    for(int j = 31; j >= 0; j--) bi = (x[j] == m) ? (j * 64 + lane) : bi;
    #pragma unroll
    for(int off = 1; off < 64; off <<= 1){ int ob = __shfl_xor(bi, off, 64); bi = min(bi, ob); }
    if(lane == s) sel = bi;
    #pragma unroll
    for(int j = 0; j < 32; j++) x[j] = (bi == j * 64 + lane) ? -3.4e38f : x[j];
  }
  if(lane < Kk) idxout[((size_t)(rowbase + row)) * Kk + lane] = sel;
}

// ---------------- f32 -> (hi,lo) bf16 split
__global__ void cvt_k(const float* __restrict__ in, ushort* __restrict__ hi,
                      ushort* __restrict__ lo, int n4){
  int i = blockIdx.x * 256 + threadIdx.x;
  if(i >= n4) return;
  float4 v = *(const float4*)(in + (size_t)i * 4);
  float vv[4] = {v.x, v.y, v.z, v.w};
  ushort h[4], l[4];
  #pragma unroll
  for(int j = 0; j < 4; j++){
    h[j] = f2bf(vv[j]);
    float r = vv[j] - bf2f(h[j]);
    l[j] = f2bf(r);
  }
  ushort4 uh, ul;
  uh.x = h[0]; uh.y = h[1]; uh.z = h[2]; uh.w = h[3];
  ul.x = l[0]; ul.y = l[1]; ul.z = l[2]; ul.w = l[3];
  ((ushort4*)hi)[i] = uh;
  ((ushort4*)lo)[i] = ul;
}

// ---------------- final conv via split-bf16 MFMA + fused col-max
#define LDH 40
__global__ __launch_bounds__(256) void fc3_k(const ushort* __restrict__ fH, const ushort* __restrict__ fL,
        const ushort* __restrict__ wH, const ushort* __restrict__ wL,
        float* __restrict__ pmax){
  __shared__ ushort aH[128 * LDH], aL[128 * LDH], bH[128 * LDH], bL[128 * LDH];
  __shared__ float red[2][128];
  int t = threadIdx.x;
  int lane = t & 63, wid = t >> 6;
  int wm = wid >> 1, wn = wid & 1;
  int rt = blockIdx.y, o0 = blockIdx.x * 128;
  const ushort* gaH = fH + (size_t)rt * 128 * 512;
  const ushort* gaL = fL + (size_t)rt * 128 * 512;
  const ushort* gbH = wH + (size_t)o0 * 512;
  const ushort* gbL = wL + (size_t)o0 * 512;
  f32x4 acc[4][4];
  #pragma unroll
  for(int i = 0; i < 4; i++)
    #pragma unroll
    for(int j = 0; j < 4; j++)
      acc[i][j] = (f32x4){0.f, 0.f, 0.f, 0.f};
  for(int c0 = 0; c0 < 512; c0 += 32){
    #pragma unroll
    for(int p = 0; p < 2; p++){
      int r = (t >> 2) + p * 64, s = (t & 3) * 8;
      size_t go = (size_t)r * 512 + c0 + s;
      int lof = r * LDH + s;
      *(uint4*)&aH[lof] = *(const uint4*)&gaH[go];
      *(uint4*)&aL[lof] = *(const uint4*)&gaL[go];
      *(uint4*)&bH[lof] = *(const uint4*)&gbH[go];
      *(uint4*)&bL[lof] = *(const uint4*)&gbL[go];
    }
    __syncthreads();
    int koff = (lane >> 4) * 8;
    short8v AH[4], AL[4], BH[4], BL[4];
    #pragma unroll
    for(int f = 0; f < 4; f++){
      int ra = (wm * 64 + f * 16 + (lane & 15)) * LDH + koff;
      AH[f] = *(const short8v*)&aH[ra];
      AL[f] = *(const short8v*)&aL[ra];
      int rb = (wn * 64 + f * 16 + (lane & 15)) * LDH + koff;
      BH[f] = *(const short8v*)&bH[rb];
      BL[f] = *(const short8v*)&bL[rb];
    }
    #pragma unroll
    for(int i = 0; i < 4; i++)
      #pragma unroll
      for(int j = 0; j < 4; j++){
        acc[i][j] = __builtin_amdgcn_mfma_f32_16x16x32_bf16(AH[i], BH[j], acc[i][j], 0, 0, 0);
        acc[i][j] = __builtin_amdgcn_mfma_f32_16x16x32_bf16(AH[i], BL[j], acc[i][j], 0, 0, 0);
        acc[i][j] = __builtin_amdgcn_mfma_f32_16x16x32_bf16(AL[i], BH[j], acc[i][j], 0, 0, 0);
      }
    __syncthreads();
  }
  #pragma unroll
  for(int j = 0; j < 4; j++){
    float m = -3.4e38f;
    #pragma unroll
    for(int i = 0; i < 4; i++)
      m = fmaxf(m, fmaxf(fmaxf(acc[i][j][0], acc[i][j][1]), fmaxf(acc[i][j][2], acc[i][j][3])));
    m = fmaxf(m, __shfl_xor(m, 16, 64));
    m = fmaxf(m, __shfl_xor(m, 32, 64));
    if(lane < 16) red[wm][wn * 64 + j * 16 + lane] = m;
  }
  __syncthreads();
  if(t < 128)
    pmax[(size_t)rt * 1024 + o0 + t] = fmaxf(red[0][t], red[1][t]);
}

__global__ void fc_reduce_k(const float* __restrict__ pmax, const float* __restrict__ bf,
                            float* __restrict__ out){
  int i = blockIdx.x * 256 + threadIdx.x;
  if(i >= Bb * 1024) return;
  int b = i >> 10, o = i & 1023;
  float m = -3.4e38f;
  for(int rt = b * 16; rt < b * 16 + 16; rt++) m = fmaxf(m, pmax[(size_t)rt * 1024 + o]);
  out[i] = m + bf[o];
}

// =====================================================================
extern "C" void kernel_launch(void* const* d_in, const int* in_sizes, int n_in,
                              void* d_out, int out_size, void* d_ws, size_t ws_size,
                              hipStream_t stream){
  const float* x  = (const float*)d_in[0];
  const int* idx0 = (const int*)d_in[1];
  const float* Wl[4] = {(const float*)d_in[2], (const float*)d_in[5], (const float*)d_in[8],  (const float*)d_in[11]};
  const float* Gl[4] = {(const float*)d_in[3], (const float*)d_in[6], (const float*)d_in[9],  (const float*)d_in[12]};
  const float* Bl[4] = {(const float*)d_in[4], (const float*)d_in[7], (const float*)d_in[10], (const float*)d_in[13]};
  const float* wf = (const float*)d_in[14];
  const float* bf = (const float*)d_in[15];
  float* out = (float*)d_out;

  char* base = (char*)d_ws;
  size_t off = 0;
  auto alloc = [&](size_t bytes) -> char* {
    char* p = base + off;
    off += (bytes + 255) & ~(size_t)255;
    return p;
  };
  float* feat = (float*)alloc((size_t)Bb * Nn * FC * 4);
  float* Abuf = (float*)alloc((size_t)Bb * Nn * 256 * 4);
  float* Bbuf = (float*)alloc((size_t)Bb * Nn * 256 * 4);
  float* Mn   = (float*)alloc((size_t)Bb * Nn * 256 * 4);
  int*   idxb = (int*)  alloc((size_t)Bb * Nn * Kk * 4);
  float* xx   = (float*)alloc((size_t)Bb * Nn * 4);
  float* Wt1  = (float*)alloc(128 * 256 * 4);
  float* Wt2  = (float*)alloc(128 * 256 * 4);
  float* psum = (float*)alloc((size_t)1024 * 256 * 4);
  float* psq  = (float*)alloc((size_t)1024 * 256 * 4);
  float* scal = (float*)alloc(256 * 4);
  float* shft = (float*)alloc(256 * 4);
  float* pmax = (float*)alloc((size_t)128 * 1024 * 4);
  float* nd   = (float*)(base + off);
  bool fullND = (off + (size_t)Bb * Nn * Nn * 4) <= ws_size;

  ushort* featH = (ushort*)Abuf;
  ushort* featL = (ushort*)Bbuf;
  ushort* wfH   = (ushort*)Mn;
  ushort* wfL   = ((ushort*)Mn) + (size_t)1024 * 512;

  // ---------------- Layer 0 (given indices, C=3, O=64, out at feat+0)
  wt_prep_k<<<(3 * 64 + 255) / 256, 256, 0, stream>>>(Wl[0], Wt1, Wt2, 3, 64);
  gemm_ab_k<3, 64><<<Bb * Nn / 16, 256, 0, stream>>>(x, 3, Wt1, Wt2, Abuf, Bbuf);
  edge_reduce_k<64><<<Bb * Nn / 64, 256, 0, stream>>>(Abuf, Bbuf, idx0, feat + 0, Mn, psum, psq);
  bn_finalize2_k<<<64, 64, 0, stream>>>(psum, psq, Gl[0], Bl[0], scal, shft, 64, Bb * Nn / 64);
  bn_apply_k<<<(Bb * Nn * 64) / 256, 256, 0, stream>>>(feat + 0, Mn, scal, shft, Gl[0], 64);

  #define RUN_KNN(CIN, OFFIN)                                                            \
    rownorm_k<<<Bb * Nn / 256, 256, 0, stream>>>(feat + (OFFIN), xx, (CIN));             \
    if(fullND){                                                                          \
      gram2_k<CIN><<<dim3(16, 16, 8), 256, 0, stream>>>(feat + (OFFIN), xx, nd, 0);      \
      topk_w<<<Bb * Nn / 4, 256, 0, stream>>>(nd, idxb, 0);                              \
    } else {                                                                             \
      for(int bb = 0; bb < Bb; bb++){                                                    \
        gram2_k<CIN><<<dim3(16, 16, 1), 256, 0, stream>>>(feat + (OFFIN), xx, nd, bb);   \
        topk_w<<<Nn / 4, 256, 0, stream>>>(nd, idxb, bb * Nn);                           \
      }                                                                                  \
    }

  // ---------------- Layer 1
  RUN_KNN(64, 0)
  wt_prep_k<<<(64 * 64 + 255) / 256, 256, 0, stream>>>(Wl[1], Wt1, Wt2, 64, 64);
  gemm_ab_k<64, 64><<<Bb * Nn / 16, 256, 0, stream>>>(feat + 0, FC, Wt1, Wt2, Abuf, Bbuf);
  edge_reduce_k<64><<<Bb * Nn / 64, 256, 0, stream>>>(Abuf, Bbuf, idxb, feat + 64, Mn, psum, psq);
  bn_finalize2_k<<<64, 64, 0, stream>>>(psum, psq, Gl[1], Bl[1], scal, shft, 64, Bb * Nn / 64);
  bn_apply_k<<<(Bb * Nn * 64) / 256, 256, 0, stream>>>(feat + 64, Mn, scal, shft, Gl[1], 64);

  // ---------------- Layer 2
  RUN_KNN(64, 64)
  wt_prep_k<<<(64 * 128 + 255) / 256, 256, 0, stream>>>(Wl[2], Wt1, Wt2, 64, 128);
  gemm_ab_k<64, 128><<<Bb * Nn / 16, 256, 0, stream>>>(feat + 64, FC, Wt1, Wt2, Abuf, Bbuf);
  edge_reduce_k<128><<<Bb * Nn / 32, 256, 0, stream>>>(Abuf, Bbuf, idxb, feat + 128, Mn, psum, psq);
  bn_finalize2_k<<<128, 64, 0, stream>>>(psum, psq, Gl[2], Bl[2], scal, shft, 128, Bb * Nn / 32);
  bn_apply_k<<<(Bb * Nn * 128) / 256, 256, 0, stream>>>(feat + 128, Mn, scal, shft, Gl[2], 128);

  // ---------------- Layer 3
  RUN_KNN(128, 128)
  wt_prep_k<<<(128 * 256 + 255) / 256, 256, 0, stream>>>(Wl[3], Wt1, Wt2, 128, 256);
  gemm_ab_k<128, 256><<<Bb * Nn / 16, 256, 0, stream>>>(feat + 128, FC, Wt1, Wt2, Abuf, Bbuf);
  edge_reduce_k<256><<<Bb * Nn / 16, 256, 0, stream>>>(Abuf, Bbuf, idxb, feat + 256, Mn, psum, psq);
  bn_finalize2_k<<<256, 64, 0, stream>>>(psum, psq, Gl[3], Bl[3], scal, shft, 256, Bb * Nn / 16);
  bn_apply_k<<<(Bb * Nn * 256) / 256, 256, 0, stream>>>(feat + 256, Mn, scal, shft, Gl[3], 256);

  // ---------------- Final 1x1 conv (split-bf16 MFMA) + global max pool
  cvt_k<<<(Bb * Nn * FC / 4 + 255) / 256, 256, 0, stream>>>(feat, featH, featL, Bb * Nn * FC / 4);
  cvt_k<<<(1024 * 512 / 4 + 255) / 256, 256, 0, stream>>>(wf, wfH, wfL, 1024 * 512 / 4);
  fc3_k<<<dim3(8, 128), 256, 0, stream>>>(featH, featL, wfH, wfL, pmax);
  fc_reduce_k<<<(Bb * 1024 + 255) / 256, 256, 0, stream>>>(pmax, bf, out);
  #undef RUN_KNN
}

// Round 10
// 796.662 us; speedup vs baseline: 2.3048x; 1.0896x over previous
//
#include <hip/hip_runtime.h>
#include <cstdint>

#define Bb 8
#define Nn 2048
#define Kk 20
#define FC 512
#define EPSc 1e-5f
#define SLOPEc 0.2f

#define TS 128
#define KP 32
#define LDT2 36

typedef __attribute__((ext_vector_type(8))) short short8v;
typedef __attribute__((ext_vector_type(4))) float f32x4;

static __device__ __forceinline__ float leaky(float y){ return y >= 0.f ? y : SLOPEc * y; }

static __device__ __forceinline__ ushort f2bf(float x){
  uint u = __float_as_uint(x);
  return (ushort)((u + 0x7fffu + ((u >> 16) & 1u)) >> 16);
}
static __device__ __forceinline__ float bf2f(ushort b){
  return __uint_as_float(((uint)b) << 16);
}

// ---------------- Wt prep: Wt1[c][o] = W[o][c]; Wt2[c][o] = W[o][C+c]-W[o][c]
__global__ void wt_prep_k(const float* __restrict__ W, float* __restrict__ Wt1,
                          float* __restrict__ Wt2, int C, int O){
  int i = blockIdx.x * 256 + threadIdx.x;
  if(i >= C * O) return;
  int c = i / O, o = i - c * O;
  float w1 = W[o * 2 * C + c];
  float w2 = W[o * 2 * C + C + c];
  Wt1[c * O + o] = w1;
  Wt2[c * O + o] = w2 - w1;
}

// ---------------- A = h·W1^T ; Bc = h·(W2-W1)^T   (16 rows per block)
template<int C, int O>
__global__ __launch_bounds__(256) void gemm_ab_k(const float* __restrict__ h, int hstride,
                    const float* __restrict__ Wt1, const float* __restrict__ Wt2,
                    float* __restrict__ A, float* __restrict__ Bc){
  constexpr int NG = 256 / O;
  constexpr int ROWS = 16;
  constexpr int RPG = ROWS / NG;
  __shared__ float xs[ROWS][C];
  int t = threadIdx.x;
  int row0 = blockIdx.x * ROWS;
  for(int i = t; i < ROWS * C; i += 256){
    int r = i / C, c = i - r * C;
    xs[r][c] = h[(size_t)(row0 + r) * hstride + c];
  }
  __syncthreads();
  int o = t % O, g = t / O;
  float accA[RPG], accB[RPG];
  #pragma unroll
  for(int r = 0; r < RPG; r++){ accA[r] = 0.f; accB[r] = 0.f; }
  for(int c = 0; c < C; c++){
    float wa = Wt1[c * O + o], wb = Wt2[c * O + o];
    #pragma unroll
    for(int r = 0; r < RPG; r++){
      float x = xs[g * RPG + r][c];
      accA[r] = fmaf(x, wa, accA[r]);
      accB[r] = fmaf(x, wb, accB[r]);
    }
  }
  for(int r = 0; r < RPG; r++){
    size_t id = (size_t)(row0 + g * RPG + r) * O + o;
    A[id] = accA[r];
    Bc[id] = accB[r];
  }
}

// ---------------- gather + k-reduce (max/min) + DETERMINISTIC BN partials
template<int O>
__global__ __launch_bounds__(256) void edge_reduce_k(const float* __restrict__ A,
                       const float* __restrict__ Bc, const int* __restrict__ idx,
                       float* __restrict__ outMax, float* __restrict__ outMin,
                       float* __restrict__ psum, float* __restrict__ psq){
  constexpr int NG = 256 / O;
  constexpr int RPG = 16;
  constexpr int ROWS = NG * RPG;
  int t = threadIdx.x;
  int o = t % O, g = t / O;
  int blocks_per_b = Nn / ROWS;
  int b = blockIdx.x / blocks_per_b;
  int n0 = (blockIdx.x % blocks_per_b) * ROWS;
  float tsum = 0.f, tsq = 0.f;
  for(int r = 0; r < RPG; r++){
    int n = n0 + g * RPG + r;
    size_t rowid = (size_t)b * Nn + n;
    const int* ip = idx + rowid * Kk;
    float bv = Bc[rowid * O + o];
    float amax = -3.4e38f, amin = 3.4e38f, asum = 0.f, asq = 0.f;
    for(int k = 0; k < Kk; k++){
      int nb = ip[k];
      float a = A[((size_t)b * Nn + nb) * O + o];
      amax = fmaxf(amax, a);
      amin = fminf(amin, a);
      asum += a;
      asq = fmaf(a, a, asq);
    }
    outMax[rowid * FC + o] = amax + bv;
    outMin[rowid * O + o]  = amin + bv;
    tsum += asum + (float)Kk * bv;
    tsq  += asq + 2.f * bv * asum + (float)Kk * bv * bv;
  }
  __shared__ float red[256];
  red[t] = tsum; __syncthreads();
  if(g == 0){
    float s = 0.f;
    for(int gg = 0; gg < NG; gg++) s += red[gg * O + o];
    psum[(size_t)blockIdx.x * O + o] = s;
  }
  __syncthreads();
  red[t] = tsq; __syncthreads();
  if(g == 0){
    float s = 0.f;
    for(int gg = 0; gg < NG; gg++) s += red[gg * O + o];
    psq[(size_t)blockIdx.x * O + o] = s;
  }
}

// ---------------- deterministic BN finalize: one wave per channel
__global__ __launch_bounds__(64) void bn_finalize2_k(const float* __restrict__ psum,
                              const float* __restrict__ psq,
                              const float* __restrict__ gam, const float* __restrict__ bet,
                              float* __restrict__ scale, float* __restrict__ shift,
                              int O, int nb){
  int o = blockIdx.x;
  int t = threadIdx.x;
  float s = 0.f, q = 0.f;
  for(int bk = t; bk < nb; bk += 64){
    s += psum[(size_t)bk * O + o];
    q += psq[(size_t)bk * O + o];
  }
  #pragma unroll
  for(int off2 = 1; off2 < 64; off2 <<= 1){
    s += __shfl_xor(s, off2, 64);
    q += __shfl_xor(q, off2, 64);
  }
  if(t == 0){
    float cnt = (float)Bb * (float)Nn * (float)Kk;
    float mean = s / cnt;
    float var = q / cnt - mean * mean;
    var = fmaxf(var, 0.f);
    float sc = gam[o] * rsqrtf(var + EPSc);
    scale[o] = sc;
    shift[o] = bet[o] - mean * sc;
  }
}

__global__ void bn_apply_k(float* __restrict__ featsl, const float* __restrict__ Mn,
                           const float* __restrict__ scale, const float* __restrict__ shift,
                           const float* __restrict__ gam, int O){
  int i = blockIdx.x * 256 + threadIdx.x;
  if(i >= Bb * Nn * O) return;
  int o = i % O;
  size_t row = (size_t)(i / O);
  float v = (gam[o] >= 0.f) ? featsl[row * FC + o] : Mn[row * O + o];
  float y = fmaf(scale[o], v, shift[o]);
  featsl[row * FC + o] = leaky(y);
}

// ---------------- row squared norms
__global__ void rownorm_k(const float* __restrict__ featsl, float* __restrict__ xx, int C){
  int i = blockIdx.x * 256 + threadIdx.x;
  if(i >= Bb * Nn) return;
  const float* p = featsl + (size_t)i * FC;
  float s = 0.f;
  for(int c = 0; c < C; c++) s = fmaf(p[c], p[c], s);
  xx[i] = s;
}

// ---------------- symmetric neg_dist, upper-triangle 128x128 tiles.
// BIT-EXACTNESS vs the full R8 kernel (now provable — BN is deterministic, no
// atomic-lottery confound):
//  * acc bit-equal under operand swap: fmaf(a,b,c)==fmaf(b,a,c), identical
//    c-ascending chain, identical staging order.
//  * normal store keeps R8's exact text: 2.f*acc - xn[i] - xm[j]
//  * mirror store: 2.f*acc - xm[j] - xn[i]  == what the full kernel computes at
//    the transposed position (its row-side xx IS xx[m]); left-assoc both; and
//    2.f*acc is an exact pow-2 product, so contraction cannot change bits.
// Mirror staged through LDS transpose REUSING fa/fb (no extra LDS -> occupancy
// preserved, unlike R5's 70KB version), stored as coalesced float4 rows.
template<int CIN>
__global__ __launch_bounds__(256) void gram_sym3_k(const float* __restrict__ feat,
                     const float* __restrict__ xx, float* __restrict__ nd, int b0){
  int b = b0 + blockIdx.z;
  float* ndb = nd + (size_t)blockIdx.z * Nn * Nn;
  int id = blockIdx.x;
  int iB = 0;
  while(id >= 16 - iB){ id -= 16 - iB; iB++; }
  int jB = iB + id;
  int n0 = iB * TS, m0 = jB * TS;
  __shared__ float smem[2 * TS * LDT2];   // fa | fb ; reused as LT (64x132)
  float* fa = smem;
  float* fb = smem + TS * LDT2;
  float* LT = smem;
  int t = threadIdx.x, tx = t & 15, ty = t >> 4;
  float acc[8][8] = {};
  const float* Abase = feat + ((size_t)b * Nn + n0) * FC;
  const float* Bbase = feat + ((size_t)b * Nn + m0) * FC;
  for(int c0 = 0; c0 < CIN; c0 += KP){
    #pragma unroll
    for(int p = 0; p < 4; p++){
      int f = t + p * 256;
      int n = f >> 3, c4 = (f & 7) << 2;
      float4 va = *(const float4*)(Abase + (size_t)n * FC + c0 + c4);
      float4 vb = *(const float4*)(Bbase + (size_t)n * FC + c0 + c4);
      *(float4*)&fa[n * LDT2 + c4] = va;
      *(float4*)&fb[n * LDT2 + c4] = vb;
    }
    __syncthreads();
    #pragma unroll
    for(int c4 = 0; c4 < KP; c4 += 4){
      float4 a4[8];
      #pragma unroll
      for(int i = 0; i < 8; i++) a4[i] = *(const float4*)&fa[(ty + 16 * i) * LDT2 + c4];
      #pragma unroll
      for(int j = 0; j < 8; j++){
        float4 b4 = *(const float4*)&fb[(tx + 16 * j) * LDT2 + c4];
        #pragma unroll
        for(int i = 0; i < 8; i++) acc[i][j] = fmaf(a4[i].x, b4.x, acc[i][j]);
        #pragma unroll
        for(int i = 0; i < 8; i++) acc[i][j] = fmaf(a4[i].y, b4.y, acc[i][j]);
        #pragma unroll
        for(int i = 0; i < 8; i++) acc[i][j] = fmaf(a4[i].z, b4.z, acc[i][j]);
        #pragma unroll
        for(int i = 0; i < 8; i++) acc[i][j] = fmaf(a4[i].w, b4.w, acc[i][j]);
      }
    }
    __syncthreads();
  }
  float xn[8], xm[8];
  #pragma unroll
  for(int i = 0; i < 8; i++) xn[i] = xx[(size_t)b * Nn + n0 + ty + 16 * i];
  #pragma unroll
  for(int j = 0; j < 8; j++) xm[j] = xx[(size_t)b * Nn + m0 + tx + 16 * j];
  // normal tile store: text identical to R8's full kernel
  #pragma unroll
  for(int i = 0; i < 8; i++){
    size_t rbase = (size_t)(n0 + ty + 16 * i) * Nn + m0;
    #pragma unroll
    for(int j = 0; j < 8; j++)
      ndb[rbase + tx + 16 * j] = 2.f * acc[i][j] - xn[i] - xm[j];
  }
  if(iB != jB){
    #pragma unroll
    for(int h = 0; h < 2; h++){
      __syncthreads();
      #pragma unroll
      for(int jj = 0; jj < 4; jj++){
        int j = h * 4 + jj;
        int c = tx + 16 * jj;               // local col 0..63 (global m0+64h+c)
        #pragma unroll
        for(int i = 0; i < 8; i++){
          int r = ty + 16 * i;              // local row 0..127 (global n0+r)
          LT[c * 132 + r] = 2.f * acc[i][j] - xm[j] - xn[i];
        }
      }
      __syncthreads();
      int c2 = t >> 2;
      int rq = t & 3;
      size_t gr = (size_t)(m0 + 64 * h + c2) * Nn + n0;
      #pragma unroll
      for(int q = 0; q < 8; q++){
        int r4 = rq * 4 + q * 16;
        float4 v = *(const float4*)&LT[c2 * 132 + r4];
        *(float4*)&ndb[gr + r4] = v;
      }
    }
  }
}

// ---------------- wave-per-row top-K (no barriers, registers only)
__global__ __launch_bounds__(256) void topk_w(const float* __restrict__ nd,
                                              int* __restrict__ idxout, int rowbase){
  int wid = threadIdx.x >> 6, lane = threadIdx.x & 63;
  int row = blockIdx.x * 4 + wid;
  const float* src = nd + (size_t)row * Nn;
  float x[32];
  #pragma unroll
  for(int j = 0; j < 32; j++) x[j] = src[j * 64 + lane];
  int sel = 0;
  for(int s = 0; s < Kk; s++){
    float m = x[0];
    #pragma unroll
    for(int j = 1; j < 32; j++) m = fmaxf(m, x[j]);
    #pragma unroll
    for(int off = 1; off < 64; off <<= 1) m = fmaxf(m, __shfl_xor(m, off, 64));
    int bi = 0x7fffffff;
    #pragma unroll
    for(int j = 31; j >= 0; j--) bi = (x[j] == m) ? (j * 64 + lane) : bi;
    #pragma unroll
    for(int off = 1; off < 64; off <<= 1){ int ob = __shfl_xor(bi, off, 64); bi = min(bi, ob); }
    if(lane == s) sel = bi;
    #pragma unroll
    for(int j = 0; j < 32; j++) x[j] = (bi == j * 64 + lane) ? -3.4e38f : x[j];
  }
  if(lane < Kk) idxout[((size_t)(rowbase + row)) * Kk + lane] = sel;
}

// ---------------- f32 -> (hi,lo) bf16 split (for fc)
__global__ void cvt_k(const float* __restrict__ in, ushort* __restrict__ hi,
                      ushort* __restrict__ lo, int n4){
  int i = blockIdx.x * 256 + threadIdx.x;
  if(i >= n4) return;
  float4 v = *(const float4*)(in + (size_t)i * 4);
  float vv[4] = {v.x, v.y, v.z, v.w};
  ushort h[4], l[4];
  #pragma unroll
  for(int j = 0; j < 4; j++){
    h[j] = f2bf(vv[j]);
    float r = vv[j] - bf2f(h[j]);
    l[j] = f2bf(r);
  }
  ushort4 uh, ul;
  uh.x = h[0]; uh.y = h[1]; uh.z = h[2]; uh.w = h[3];
  ul.x = l[0]; ul.y = l[1]; ul.z = l[2]; ul.w = l[3];
  ((ushort4*)hi)[i] = uh;
  ((ushort4*)lo)[i] = ul;
}

// ---------------- final conv via split-bf16 MFMA + fused col-max
#define LDH 40
__global__ __launch_bounds__(256) void fc3_k(const ushort* __restrict__ fH, const ushort* __restrict__ fL,
        const ushort* __restrict__ wH, const ushort* __restrict__ wL,
        float* __restrict__ pmax){
  __shared__ ushort aH[128 * LDH], aL[128 * LDH], bH[128 * LDH], bL[128 * LDH];
  __shared__ float red[2][128];
  int t = threadIdx.x;
  int lane = t & 63, wid = t >> 6;
  int wm = wid >> 1, wn = wid & 1;
  int rt = blockIdx.y, o0 = blockIdx.x * 128;
  const ushort* gaH = fH + (size_t)rt * 128 * 512;
  const ushort* gaL = fL + (size_t)rt * 128 * 512;
  const ushort* gbH = wH + (size_t)o0 * 512;
  const ushort* gbL = wL + (size_t)o0 * 512;
  f32x4 acc[4][4];
  #pragma unroll
  for(int i = 0; i < 4; i++)
    #pragma unroll
    for(int j = 0; j < 4; j++)
      acc[i][j] = (f32x4){0.f, 0.f, 0.f, 0.f};
  for(int c0 = 0; c0 < 512; c0 += 32){
    #pragma unroll
    for(int p = 0; p < 2; p++){
      int r = (t >> 2) + p * 64, s = (t & 3) * 8;
      size_t go = (size_t)r * 512 + c0 + s;
      int lof = r * LDH + s;
      *(uint4*)&aH[lof] = *(const uint4*)&gaH[go];
      *(uint4*)&aL[lof] = *(const uint4*)&gaL[go];
      *(uint4*)&bH[lof] = *(const uint4*)&gbH[go];
      *(uint4*)&bL[lof] = *(const uint4*)&gbL[go];
    }
    __syncthreads();
    int koff = (lane >> 4) * 8;
    short8v AH[4], AL[4], BH[4], BL[4];
    #pragma unroll
    for(int f = 0; f < 4; f++){
      int ra = (wm * 64 + f * 16 + (lane & 15)) * LDH + koff;
      AH[f] = *(const short8v*)&aH[ra];
      AL[f] = *(const short8v*)&aL[ra];
      int rb = (wn * 64 + f * 16 + (lane & 15)) * LDH + koff;
      BH[f] = *(const short8v*)&bH[rb];
      BL[f] = *(const short8v*)&bL[rb];
    }
    #pragma unroll
    for(int i = 0; i < 4; i++)
      #pragma unroll
      for(int j = 0; j < 4; j++){
        acc[i][j] = __builtin_amdgcn_mfma_f32_16x16x32_bf16(AH[i], BH[j], acc[i][j], 0, 0, 0);
        acc[i][j] = __builtin_amdgcn_mfma_f32_16x16x32_bf16(AH[i], BL[j], acc[i][j], 0, 0, 0);
        acc[i][j] = __builtin_amdgcn_mfma_f32_16x16x32_bf16(AL[i], BH[j], acc[i][j], 0, 0, 0);
      }
    __syncthreads();
  }
  #pragma unroll
  for(int j = 0; j < 4; j++){
    float m = -3.4e38f;
    #pragma unroll
    for(int i = 0; i < 4; i++)
      m = fmaxf(m, fmaxf(fmaxf(acc[i][j][0], acc[i][j][1]), fmaxf(acc[i][j][2], acc[i][j][3])));
    m = fmaxf(m, __shfl_xor(m, 16, 64));
    m = fmaxf(m, __shfl_xor(m, 32, 64));
    if(lane < 16) red[wm][wn * 64 + j * 16 + lane] = m;
  }
  __syncthreads();
  if(t < 128)
    pmax[(size_t)rt * 1024 + o0 + t] = fmaxf(red[0][t], red[1][t]);
}

__global__ void fc_reduce_k(const float* __restrict__ pmax, const float* __restrict__ bf,
                            float* __restrict__ out){
  int i = blockIdx.x * 256 + threadIdx.x;
  if(i >= Bb * 1024) return;
  int b = i >> 10, o = i & 1023;
  float m = -3.4e38f;
  for(int rt = b * 16; rt < b * 16 + 16; rt++) m = fmaxf(m, pmax[(size_t)rt * 1024 + o]);
  out[i] = m + bf[o];
}

// =====================================================================
extern "C" void kernel_launch(void* const* d_in, const int* in_sizes, int n_in,
                              void* d_out, int out_size, void* d_ws, size_t ws_size,
                              hipStream_t stream){
  const float* x  = (const float*)d_in[0];
  const int* idx0 = (const int*)d_in[1];
  const float* Wl[4] = {(const float*)d_in[2], (const float*)d_in[5], (const float*)d_in[8],  (const float*)d_in[11]};
  const float* Gl[4] = {(const float*)d_in[3], (const float*)d_in[6], (const float*)d_in[9],  (const float*)d_in[12]};
  const float* Bl[4] = {(const float*)d_in[4], (const float*)d_in[7], (const float*)d_in[10], (const float*)d_in[13]};
  const float* wf = (const float*)d_in[14];
  const float* bf = (const float*)d_in[15];
  float* out = (float*)d_out;

  char* base = (char*)d_ws;
  size_t off = 0;
  auto alloc = [&](size_t bytes) -> char* {
    char* p = base + off;
    off += (bytes + 255) & ~(size_t)255;
    return p;
  };
  float* feat = (float*)alloc((size_t)Bb * Nn * FC * 4);
  float* Abuf = (float*)alloc((size_t)Bb * Nn * 256 * 4);
  float* Bbuf = (float*)alloc((size_t)Bb * Nn * 256 * 4);
  float* Mn   = (float*)alloc((size_t)Bb * Nn * 256 * 4);
  int*   idxb = (int*)  alloc((size_t)Bb * Nn * Kk * 4);
  float* xx   = (float*)alloc((size_t)Bb * Nn * 4);
  float* Wt1  = (float*)alloc(128 * 256 * 4);
  float* Wt2  = (float*)alloc(128 * 256 * 4);
  float* psum = (float*)alloc((size_t)1024 * 256 * 4);
  float* psq  = (float*)alloc((size_t)1024 * 256 * 4);
  float* scal = (float*)alloc(256 * 4);
  float* shft = (float*)alloc(256 * 4);
  float* pmax = (float*)alloc((size_t)128 * 1024 * 4);
  float* nd   = (float*)(base + off);
  bool fullND = (off + (size_t)Bb * Nn * Nn * 4) <= ws_size;

  ushort* featH = (ushort*)Abuf;
  ushort* featL = (ushort*)Bbuf;
  ushort* wfH   = (ushort*)Mn;
  ushort* wfL   = ((ushort*)Mn) + (size_t)1024 * 512;

  // ---------------- Layer 0 (given indices, C=3, O=64, out at feat+0)
  wt_prep_k<<<(3 * 64 + 255) / 256, 256, 0, stream>>>(Wl[0], Wt1, Wt2, 3, 64);
  gemm_ab_k<3, 64><<<Bb * Nn / 16, 256, 0, stream>>>(x, 3, Wt1, Wt2, Abuf, Bbuf);
  edge_reduce_k<64><<<Bb * Nn / 64, 256, 0, stream>>>(Abuf, Bbuf, idx0, feat + 0, Mn, psum, psq);
  bn_finalize2_k<<<64, 64, 0, stream>>>(psum, psq, Gl[0], Bl[0], scal, shft, 64, Bb * Nn / 64);
  bn_apply_k<<<(Bb * Nn * 64) / 256, 256, 0, stream>>>(feat + 0, Mn, scal, shft, Gl[0], 64);

  #define RUN_KNN(CIN, OFFIN)                                                               \
    rownorm_k<<<Bb * Nn / 256, 256, 0, stream>>>(feat + (OFFIN), xx, (CIN));                \
    if(fullND){                                                                             \
      gram_sym3_k<CIN><<<dim3(136, 1, 8), 256, 0, stream>>>(feat + (OFFIN), xx, nd, 0);     \
      topk_w<<<Bb * Nn / 4, 256, 0, stream>>>(nd, idxb, 0);                                 \
    } else {                                                                                \
      for(int bb = 0; bb < Bb; bb++){                                                       \
        gram_sym3_k<CIN><<<dim3(136, 1, 1), 256, 0, stream>>>(feat + (OFFIN), xx, nd, bb);  \
        topk_w<<<Nn / 4, 256, 0, stream>>>(nd, idxb, bb * Nn);                              \
      }                                                                                     \
    }

  // ---------------- Layer 1
  RUN_KNN(64, 0)
  wt_prep_k<<<(64 * 64 + 255) / 256, 256, 0, stream>>>(Wl[1], Wt1, Wt2, 64, 64);
  gemm_ab_k<64, 64><<<Bb * Nn / 16, 256, 0, stream>>>(feat + 0, FC, Wt1, Wt2, Abuf, Bbuf);
  edge_reduce_k<64><<<Bb * Nn / 64, 256, 0, stream>>>(Abuf, Bbuf, idxb, feat + 64, Mn, psum, psq);
  bn_finalize2_k<<<64, 64, 0, stream>>>(psum, psq, Gl[1], Bl[1], scal, shft, 64, Bb * Nn / 64);
  bn_apply_k<<<(Bb * Nn * 64) / 256, 256, 0, stream>>>(feat + 64, Mn, scal, shft, Gl[1], 64);

  // ---------------- Layer 2
  RUN_KNN(64, 64)
  wt_prep_k<<<(64 * 128 + 255) / 256, 256, 0, stream>>>(Wl[2], Wt1, Wt2, 64, 128);
  gemm_ab_k<64, 128><<<Bb * Nn / 16, 256, 0, stream>>>(feat + 64, FC, Wt1, Wt2, Abuf, Bbuf);
  edge_reduce_k<128><<<Bb * Nn / 32, 256, 0, stream>>>(Abuf, Bbuf, idxb, feat + 128, Mn, psum, psq);
  bn_finalize2_k<<<128, 64, 0, stream>>>(psum, psq, Gl[2], Bl[2], scal, shft, 128, Bb * Nn / 32);
  bn_apply_k<<<(Bb * Nn * 128) / 256, 256, 0, stream>>>(feat + 128, Mn, scal, shft, Gl[2], 128);

  // ---------------- Layer 3
  RUN_KNN(128, 128)
  wt_prep_k<<<(128 * 256 + 255) / 256, 256, 0, stream>>>(Wl[3], Wt1, Wt2, 128, 256);
  gemm_ab_k<128, 256><<<Bb * Nn / 16, 256, 0, stream>>>(feat + 128, FC, Wt1, Wt2, Abuf, Bbuf);
  edge_reduce_k<256><<<Bb * Nn / 16, 256, 0, stream>>>(Abuf, Bbuf, idxb, feat + 256, Mn, psum, psq);
  bn_finalize2_k<<<256, 64, 0, stream>>>(psum, psq, Gl[3], Bl[3], scal, shft, 256, Bb * Nn / 16);
  bn_apply_k<<<(Bb * Nn * 256) / 256, 256, 0, stream>>>(feat + 256, Mn, scal, shft, Gl[3], 256);

  // ---------------- Final 1x1 conv (split-bf16 MFMA) + global max pool
  cvt_k<<<(Bb * Nn * FC / 4 + 255) / 256, 256, 0, stream>>>(feat, featH, featL, Bb * Nn * FC / 4);
  cvt_k<<<(1024 * 512 / 4 + 255) / 256, 256, 0, stream>>>(wf, wfH, wfL, 1024 * 512 / 4);
  fc3_k<<<dim3(8, 128), 256, 0, stream>>>(featH, featL, wfH, wfL, pmax);
  fc_reduce_k<<<(Bb * 1024 + 255) / 256, 256, 0, stream>>>(pmax, bf, out);
  #undef RUN_KNN
}

// Round 11
// 605.238 us; speedup vs baseline: 3.0337x; 1.3163x over previous
//
#include <hip/hip_runtime.h>
#include <cstdint>

#define Bb 8
#define Nn 2048
#define Kk 20
#define FC 512
#define EPSc 1e-5f
#define SLOPEc 0.2f

#define TS 128
#define KP 32
#define LDT2 36

typedef __attribute__((ext_vector_type(8))) short short8v;
typedef __attribute__((ext_vector_type(4))) float f32x4;

static __device__ __forceinline__ float leaky(float y){ return y >= 0.f ? y : SLOPEc * y; }

static __device__ __forceinline__ ushort f2bf(float x){
  uint u = __float_as_uint(x);
  return (ushort)((u + 0x7fffu + ((u >> 16) & 1u)) >> 16);
}
static __device__ __forceinline__ float bf2f(ushort b){
  return __uint_as_float(((uint)b) << 16);
}

// ---------------- Wt prep: Wt1[c][o] = W[o][c]; Wt2[c][o] = W[o][C+c]-W[o][c]
__global__ void wt_prep_k(const float* __restrict__ W, float* __restrict__ Wt1,
                          float* __restrict__ Wt2, int C, int O){
  int i = blockIdx.x * 256 + threadIdx.x;
  if(i >= C * O) return;
  int c = i / O, o = i - c * O;
  float w1 = W[o * 2 * C + c];
  float w2 = W[o * 2 * C + C + c];
  Wt1[c * O + o] = w1;
  Wt2[c * O + o] = w2 - w1;
}

// ---------------- A = h·W1^T ; Bc = h·(W2-W1)^T   (16 rows per block)
template<int C, int O>
__global__ __launch_bounds__(256) void gemm_ab_k(const float* __restrict__ h, int hstride,
                    const float* __restrict__ Wt1, const float* __restrict__ Wt2,
                    float* __restrict__ A, float* __restrict__ Bc){
  constexpr int NG = 256 / O;
  constexpr int ROWS = 16;
  constexpr int RPG = ROWS / NG;
  __shared__ float xs[ROWS][C];
  int t = threadIdx.x;
  int row0 = blockIdx.x * ROWS;
  for(int i = t; i < ROWS * C; i += 256){
    int r = i / C, c = i - r * C;
    xs[r][c] = h[(size_t)(row0 + r) * hstride + c];
  }
  __syncthreads();
  int o = t % O, g = t / O;
  float accA[RPG], accB[RPG];
  #pragma unroll
  for(int r = 0; r < RPG; r++){ accA[r] = 0.f; accB[r] = 0.f; }
  for(int c = 0; c < C; c++){
    float wa = Wt1[c * O + o], wb = Wt2[c * O + o];
    #pragma unroll
    for(int r = 0; r < RPG; r++){
      float x = xs[g * RPG + r][c];
      accA[r] = fmaf(x, wa, accA[r]);
      accB[r] = fmaf(x, wb, accB[r]);
    }
  }
  for(int r = 0; r < RPG; r++){
    size_t id = (size_t)(row0 + g * RPG + r) * O + o;
    A[id] = accA[r];
    Bc[id] = accB[r];
  }
}

// ---------------- gather + k-reduce (max/min) + DETERMINISTIC BN partials
template<int O>
__global__ __launch_bounds__(256) void edge_reduce_k(const float* __restrict__ A,
                       const float* __restrict__ Bc, const int* __restrict__ idx,
                       float* __restrict__ outMax, float* __restrict__ outMin,
                       float* __restrict__ psum, float* __restrict__ psq){
  constexpr int NG = 256 / O;
  constexpr int RPG = 16;
  constexpr int ROWS = NG * RPG;
  int t = threadIdx.x;
  int o = t % O, g = t / O;
  int blocks_per_b = Nn / ROWS;
  int b = blockIdx.x / blocks_per_b;
  int n0 = (blockIdx.x % blocks_per_b) * ROWS;
  float tsum = 0.f, tsq = 0.f;
  for(int r = 0; r < RPG; r++){
    int n = n0 + g * RPG + r;
    size_t rowid = (size_t)b * Nn + n;
    const int* ip = idx + rowid * Kk;
    float bv = Bc[rowid * O + o];
    float amax = -3.4e38f, amin = 3.4e38f, asum = 0.f, asq = 0.f;
    for(int k = 0; k < Kk; k++){
      int nb = ip[k];
      float a = A[((size_t)b * Nn + nb) * O + o];
      amax = fmaxf(amax, a);
      amin = fminf(amin, a);
      asum += a;
      asq = fmaf(a, a, asq);
    }
    outMax[rowid * FC + o] = amax + bv;
    outMin[rowid * O + o]  = amin + bv;
    tsum += asum + (float)Kk * bv;
    tsq  += asq + 2.f * bv * asum + (float)Kk * bv * bv;
  }
  __shared__ float red[256];
  red[t] = tsum; __syncthreads();
  if(g == 0){
    float s = 0.f;
    for(int gg = 0; gg < NG; gg++) s += red[gg * O + o];
    psum[(size_t)blockIdx.x * O + o] = s;
  }
  __syncthreads();
  red[t] = tsq; __syncthreads();
  if(g == 0){
    float s = 0.f;
    for(int gg = 0; gg < NG; gg++) s += red[gg * O + o];
    psq[(size_t)blockIdx.x * O + o] = s;
  }
}

// ---------------- deterministic BN finalize: one wave per channel
__global__ __launch_bounds__(64) void bn_finalize2_k(const float* __restrict__ psum,
                              const float* __restrict__ psq,
                              const float* __restrict__ gam, const float* __restrict__ bet,
                              float* __restrict__ scale, float* __restrict__ shift,
                              int O, int nb){
  int o = blockIdx.x;
  int t = threadIdx.x;
  float s = 0.f, q = 0.f;
  for(int bk = t; bk < nb; bk += 64){
    s += psum[(size_t)bk * O + o];
    q += psq[(size_t)bk * O + o];
  }
  #pragma unroll
  for(int off2 = 1; off2 < 64; off2 <<= 1){
    s += __shfl_xor(s, off2, 64);
    q += __shfl_xor(q, off2, 64);
  }
  if(t == 0){
    float cnt = (float)Bb * (float)Nn * (float)Kk;
    float mean = s / cnt;
    float var = q / cnt - mean * mean;
    var = fmaxf(var, 0.f);
    float sc = gam[o] * rsqrtf(var + EPSc);
    scale[o] = sc;
    shift[o] = bet[o] - mean * sc;
  }
}

__global__ void bn_apply_k(float* __restrict__ featsl, const float* __restrict__ Mn,
                           const float* __restrict__ scale, const float* __restrict__ shift,
                           const float* __restrict__ gam, int O){
  int i = blockIdx.x * 256 + threadIdx.x;
  if(i >= Bb * Nn * O) return;
  int o = i % O;
  size_t row = (size_t)(i / O);
  float v = (gam[o] >= 0.f) ? featsl[row * FC + o] : Mn[row * O + o];
  float y = fmaf(scale[o], v, shift[o]);
  featsl[row * FC + o] = leaky(y);
}

// ---------------- row squared norms
__global__ void rownorm_k(const float* __restrict__ featsl, float* __restrict__ xx, int C){
  int i = blockIdx.x * 256 + threadIdx.x;
  if(i >= Bb * Nn) return;
  const float* p = featsl + (size_t)i * FC;
  float s = 0.f;
  for(int c = 0; c < C; c++) s = fmaf(p[c], p[c], s);
  xx[i] = s;
}

// ---------------- symmetric neg_dist, upper-triangle 128x128 tiles (R10, verified
// bit-exact: absmax stable 0.15625). Mirror staged through reused LDS.
template<int CIN>
__global__ __launch_bounds__(256) void gram_sym3_k(const float* __restrict__ feat,
                     const float* __restrict__ xx, float* __restrict__ nd, int b0){
  int b = b0 + blockIdx.z;
  float* ndb = nd + (size_t)blockIdx.z * Nn * Nn;
  int id = blockIdx.x;
  int iB = 0;
  while(id >= 16 - iB){ id -= 16 - iB; iB++; }
  int jB = iB + id;
  int n0 = iB * TS, m0 = jB * TS;
  __shared__ float smem[2 * TS * LDT2];
  float* fa = smem;
  float* fb = smem + TS * LDT2;
  float* LT = smem;
  int t = threadIdx.x, tx = t & 15, ty = t >> 4;
  float acc[8][8] = {};
  const float* Abase = feat + ((size_t)b * Nn + n0) * FC;
  const float* Bbase = feat + ((size_t)b * Nn + m0) * FC;
  for(int c0 = 0; c0 < CIN; c0 += KP){
    #pragma unroll
    for(int p = 0; p < 4; p++){
      int f = t + p * 256;
      int n = f >> 3, c4 = (f & 7) << 2;
      float4 va = *(const float4*)(Abase + (size_t)n * FC + c0 + c4);
      float4 vb = *(const float4*)(Bbase + (size_t)n * FC + c0 + c4);
      *(float4*)&fa[n * LDT2 + c4] = va;
      *(float4*)&fb[n * LDT2 + c4] = vb;
    }
    __syncthreads();
    #pragma unroll
    for(int c4 = 0; c4 < KP; c4 += 4){
      float4 a4[8];
      #pragma unroll
      for(int i = 0; i < 8; i++) a4[i] = *(const float4*)&fa[(ty + 16 * i) * LDT2 + c4];
      #pragma unroll
      for(int j = 0; j < 8; j++){
        float4 b4 = *(const float4*)&fb[(tx + 16 * j) * LDT2 + c4];
        #pragma unroll
        for(int i = 0; i < 8; i++) acc[i][j] = fmaf(a4[i].x, b4.x, acc[i][j]);
        #pragma unroll
        for(int i = 0; i < 8; i++) acc[i][j] = fmaf(a4[i].y, b4.y, acc[i][j]);
        #pragma unroll
        for(int i = 0; i < 8; i++) acc[i][j] = fmaf(a4[i].z, b4.z, acc[i][j]);
        #pragma unroll
        for(int i = 0; i < 8; i++) acc[i][j] = fmaf(a4[i].w, b4.w, acc[i][j]);
      }
    }
    __syncthreads();
  }
  float xn[8], xm[8];
  #pragma unroll
  for(int i = 0; i < 8; i++) xn[i] = xx[(size_t)b * Nn + n0 + ty + 16 * i];
  #pragma unroll
  for(int j = 0; j < 8; j++) xm[j] = xx[(size_t)b * Nn + m0 + tx + 16 * j];
  #pragma unroll
  for(int i = 0; i < 8; i++){
    size_t rbase = (size_t)(n0 + ty + 16 * i) * Nn + m0;
    #pragma unroll
    for(int j = 0; j < 8; j++)
      ndb[rbase + tx + 16 * j] = 2.f * acc[i][j] - xn[i] - xm[j];
  }
  if(iB != jB){
    #pragma unroll
    for(int h = 0; h < 2; h++){
      __syncthreads();
      #pragma unroll
      for(int jj = 0; jj < 4; jj++){
        int j = h * 4 + jj;
        int c = tx + 16 * jj;
        #pragma unroll
        for(int i = 0; i < 8; i++){
          int r = ty + 16 * i;
          LT[c * 132 + r] = 2.f * acc[i][j] - xm[j] - xn[i];
        }
      }
      __syncthreads();
      int c2 = t >> 2;
      int rq = t & 3;
      size_t gr = (size_t)(m0 + 64 * h + c2) * Nn + n0;
      #pragma unroll
      for(int q = 0; q < 8; q++){
        int r4 = rq * 4 + q * 16;
        float4 v = *(const float4*)&LT[c2 * 132 + r4];
        *(float4*)&ndb[gr + r4] = v;
      }
    }
  }
}

// ---------------- top-K: threshold prefilter + exact bitonic on candidates.
// Comparison-only (no FP arithmetic on values) -> result provably identical to
// the 20-pass serial path: -0.0 never occurs in nd (RN subtraction yields +0),
// so orderable-bit packing == IEEE ordering; ties broken by lowest index via ~idx.
// T = 20th-largest of the 64 per-lane maxes => >=20 values >= T => top-20 subset
// of candidates, C >= 20. Fallback to the serial path if C > 64 (pathological).
__global__ __launch_bounds__(256) void topk_f(const float* __restrict__ nd,
                                              int* __restrict__ idxout, int rowbase){
  int wid = threadIdx.x >> 6, lane = threadIdx.x & 63;
  int row = blockIdx.x * 4 + wid;
  const float* src = nd + (size_t)row * Nn;
  __shared__ unsigned long long keys[4][64];
  unsigned long long* wkeys = keys[wid];
  float x[32];
  #pragma unroll
  for(int j = 0; j < 32; j++) x[j] = src[j * 64 + lane];
  // per-lane max
  float M = x[0];
  #pragma unroll
  for(int j = 1; j < 32; j++) M = fmaxf(M, x[j]);
  // bitonic sort (ascending) of the 64 lane maxes
  float v = M;
  #pragma unroll
  for(int k = 2; k <= 64; k <<= 1){
    #pragma unroll
    for(int j2 = k >> 1; j2 > 0; j2 >>= 1){
      float o = __shfl_xor(v, j2, 64);
      bool takeMin = (((lane & k) == 0) == ((lane & j2) == 0));
      v = takeMin ? fminf(v, o) : fmaxf(v, o);
    }
  }
  float T = __shfl(v, 44, 64);        // 20th largest lane max
  // ballot-compaction of candidates (deterministic, no atomics)
  unsigned long long lmlt = (1ull << lane) - 1ull;
  int cnt = 0;
  #pragma unroll
  for(int j = 0; j < 32; j++){
    bool pred = x[j] >= T;
    unsigned long long mk = __ballot(pred);
    if(pred){
      int pos = cnt + (int)__popcll(mk & lmlt);
      if(pos < 64){
        unsigned int bb = __float_as_uint(x[j]);
        unsigned int ord = (bb & 0x80000000u) ? ~bb : (bb | 0x80000000u);
        wkeys[pos] = ((unsigned long long)ord << 32) | (unsigned int)~(j * 64 + lane);
      }
    }
    cnt += (int)__popcll(mk);
  }
  __syncthreads();
  if(cnt <= 64){
    unsigned long long key = (lane < cnt) ? wkeys[lane] : 0ull;
    #pragma unroll
    for(int k = 2; k <= 64; k <<= 1){
      #pragma unroll
      for(int j2 = k >> 1; j2 > 0; j2 >>= 1){
        unsigned long long o = __shfl_xor(key, j2, 64);
        bool takeMin = (((lane & k) == 0) == ((lane & j2) == 0));
        bool less = key < o;
        key = (takeMin == less) ? key : o;
      }
    }
    if(lane >= 44)
      idxout[((size_t)(rowbase + row)) * Kk + (63 - lane)] = (int)~(unsigned int)key;
  } else {
    // fallback: original 20-pass serial selection (x[] still intact)
    int sel = 0;
    for(int s = 0; s < Kk; s++){
      float m = x[0];
      #pragma unroll
      for(int j = 1; j < 32; j++) m = fmaxf(m, x[j]);
      #pragma unroll
      for(int off = 1; off < 64; off <<= 1) m = fmaxf(m, __shfl_xor(m, off, 64));
      int bi = 0x7fffffff;
      #pragma unroll
      for(int j = 31; j >= 0; j--) bi = (x[j] == m) ? (j * 64 + lane) : bi;
      #pragma unroll
      for(int off = 1; off < 64; off <<= 1){ int ob = __shfl_xor(bi, off, 64); bi = min(bi, ob); }
      if(lane == s) sel = bi;
      #pragma unroll
      for(int j = 0; j < 32; j++) x[j] = (bi == j * 64 + lane) ? -3.4e38f : x[j];
    }
    if(lane < Kk) idxout[((size_t)(rowbase + row)) * Kk + lane] = sel;
  }
}

// ---------------- f32 -> (hi,lo) bf16 split (for fc)
__global__ void cvt_k(const float* __restrict__ in, ushort* __restrict__ hi,
                      ushort* __restrict__ lo, int n4){
  int i = blockIdx.x * 256 + threadIdx.x;
  if(i >= n4) return;
  float4 v = *(const float4*)(in + (size_t)i * 4);
  float vv[4] = {v.x, v.y, v.z, v.w};
  ushort h[4], l[4];
  #pragma unroll
  for(int j = 0; j < 4; j++){
    h[j] = f2bf(vv[j]);
    float r = vv[j] - bf2f(h[j]);
    l[j] = f2bf(r);
  }
  ushort4 uh, ul;
  uh.x = h[0]; uh.y = h[1]; uh.z = h[2]; uh.w = h[3];
  ul.x = l[0]; ul.y = l[1]; ul.z = l[2]; ul.w = l[3];
  ((ushort4*)hi)[i] = uh;
  ((ushort4*)lo)[i] = ul;
}

// ---------------- final conv via split-bf16 MFMA + fused col-max
#define LDH 40
__global__ __launch_bounds__(256) void fc3_k(const ushort* __restrict__ fH, const ushort* __restrict__ fL,
        const ushort* __restrict__ wH, const ushort* __restrict__ wL,
        float* __restrict__ pmax){
  __shared__ ushort aH[128 * LDH], aL[128 * LDH], bH[128 * LDH], bL[128 * LDH];
  __shared__ float red[2][128];
  int t = threadIdx.x;
  int lane = t & 63, wid = t >> 6;
  int wm = wid >> 1, wn = wid & 1;
  int rt = blockIdx.y, o0 = blockIdx.x * 128;
  const ushort* gaH = fH + (size_t)rt * 128 * 512;
  const ushort* gaL = fL + (size_t)rt * 128 * 512;
  const ushort* gbH = wH + (size_t)o0 * 512;
  const ushort* gbL = wL + (size_t)o0 * 512;
  f32x4 acc[4][4];
  #pragma unroll
  for(int i = 0; i < 4; i++)
    #pragma unroll
    for(int j = 0; j < 4; j++)
      acc[i][j] = (f32x4){0.f, 0.f, 0.f, 0.f};
  for(int c0 = 0; c0 < 512; c0 += 32){
    #pragma unroll
    for(int p = 0; p < 2; p++){
      int r = (t >> 2) + p * 64, s = (t & 3) * 8;
      size_t go = (size_t)r * 512 + c0 + s;
      int lof = r * LDH + s;
      *(uint4*)&aH[lof] = *(const uint4*)&gaH[go];
      *(uint4*)&aL[lof] = *(const uint4*)&gaL[go];
      *(uint4*)&bH[lof] = *(const uint4*)&gbH[go];
      *(uint4*)&bL[lof] = *(const uint4*)&gbL[go];
    }
    __syncthreads();
    int koff = (lane >> 4) * 8;
    short8v AH[4], AL[4], BH[4], BL[4];
    #pragma unroll
    for(int f = 0; f < 4; f++){
      int ra = (wm * 64 + f * 16 + (lane & 15)) * LDH + koff;
      AH[f] = *(const short8v*)&aH[ra];
      AL[f] = *(const short8v*)&aL[ra];
      int rb = (wn * 64 + f * 16 + (lane & 15)) * LDH + koff;
      BH[f] = *(const short8v*)&bH[rb];
      BL[f] = *(const short8v*)&bL[rb];
    }
    #pragma unroll
    for(int i = 0; i < 4; i++)
      #pragma unroll
      for(int j = 0; j < 4; j++){
        acc[i][j] = __builtin_amdgcn_mfma_f32_16x16x32_bf16(AH[i], BH[j], acc[i][j], 0, 0, 0);
        acc[i][j] = __builtin_amdgcn_mfma_f32_16x16x32_bf16(AH[i], BL[j], acc[i][j], 0, 0, 0);
        acc[i][j] = __builtin_amdgcn_mfma_f32_16x16x32_bf16(AL[i], BH[j], acc[i][j], 0, 0, 0);
      }
    __syncthreads();
  }
  #pragma unroll
  for(int j = 0; j < 4; j++){
    float m = -3.4e38f;
    #pragma unroll
    for(int i = 0; i < 4; i++)
      m = fmaxf(m, fmaxf(fmaxf(acc[i][j][0], acc[i][j][1]), fmaxf(acc[i][j][2], acc[i][j][3])));
    m = fmaxf(m, __shfl_xor(m, 16, 64));
    m = fmaxf(m, __shfl_xor(m, 32, 64));
    if(lane < 16) red[wm][wn * 64 + j * 16 + lane] = m;
  }
  __syncthreads();
  if(t < 128)
    pmax[(size_t)rt * 1024 + o0 + t] = fmaxf(red[0][t], red[1][t]);
}

__global__ void fc_reduce_k(const float* __restrict__ pmax, const float* __restrict__ bf,
                            float* __restrict__ out){
  int i = blockIdx.x * 256 + threadIdx.x;
  if(i >= Bb * 1024) return;
  int b = i >> 10, o = i & 1023;
  float m = -3.4e38f;
  for(int rt = b * 16; rt < b * 16 + 16; rt++) m = fmaxf(m, pmax[(size_t)rt * 1024 + o]);
  out[i] = m + bf[o];
}

// =====================================================================
extern "C" void kernel_launch(void* const* d_in, const int* in_sizes, int n_in,
                              void* d_out, int out_size, void* d_ws, size_t ws_size,
                              hipStream_t stream){
  const float* x  = (const float*)d_in[0];
  const int* idx0 = (const int*)d_in[1];
  const float* Wl[4] = {(const float*)d_in[2], (const float*)d_in[5], (const float*)d_in[8],  (const float*)d_in[11]};
  const float* Gl[4] = {(const float*)d_in[3], (const float*)d_in[6], (const float*)d_in[9],  (const float*)d_in[12]};
  const float* Bl[4] = {(const float*)d_in[4], (const float*)d_in[7], (const float*)d_in[10], (const float*)d_in[13]};
  const float* wf = (const float*)d_in[14];
  const float* bf = (const float*)d_in[15];
  float* out = (float*)d_out;

  char* base = (char*)d_ws;
  size_t off = 0;
  auto alloc = [&](size_t bytes) -> char* {
    char* p = base + off;
    off += (bytes + 255) & ~(size_t)255;
    return p;
  };
  float* feat = (float*)alloc((size_t)Bb * Nn * FC * 4);
  float* Abuf = (float*)alloc((size_t)Bb * Nn * 256 * 4);
  float* Bbuf = (float*)alloc((size_t)Bb * Nn * 256 * 4);
  float* Mn   = (float*)alloc((size_t)Bb * Nn * 256 * 4);
  int*   idxb = (int*)  alloc((size_t)Bb * Nn * Kk * 4);
  float* xx   = (float*)alloc((size_t)Bb * Nn * 4);
  float* Wt1  = (float*)alloc(128 * 256 * 4);
  float* Wt2  = (float*)alloc(128 * 256 * 4);
  float* psum = (float*)alloc((size_t)1024 * 256 * 4);
  float* psq  = (float*)alloc((size_t)1024 * 256 * 4);
  float* scal = (float*)alloc(256 * 4);
  float* shft = (float*)alloc(256 * 4);
  float* pmax = (float*)alloc((size_t)128 * 1024 * 4);
  float* nd   = (float*)(base + off);
  bool fullND = (off + (size_t)Bb * Nn * Nn * 4) <= ws_size;

  ushort* featH = (ushort*)Abuf;
  ushort* featL = (ushort*)Bbuf;
  ushort* wfH   = (ushort*)Mn;
  ushort* wfL   = ((ushort*)Mn) + (size_t)1024 * 512;

  // ---------------- Layer 0 (given indices, C=3, O=64, out at feat+0)
  wt_prep_k<<<(3 * 64 + 255) / 256, 256, 0, stream>>>(Wl[0], Wt1, Wt2, 3, 64);
  gemm_ab_k<3, 64><<<Bb * Nn / 16, 256, 0, stream>>>(x, 3, Wt1, Wt2, Abuf, Bbuf);
  edge_reduce_k<64><<<Bb * Nn / 64, 256, 0, stream>>>(Abuf, Bbuf, idx0, feat + 0, Mn, psum, psq);
  bn_finalize2_k<<<64, 64, 0, stream>>>(psum, psq, Gl[0], Bl[0], scal, shft, 64, Bb * Nn / 64);
  bn_apply_k<<<(Bb * Nn * 64) / 256, 256, 0, stream>>>(feat + 0, Mn, scal, shft, Gl[0], 64);

  #define RUN_KNN(CIN, OFFIN)                                                               \
    rownorm_k<<<Bb * Nn / 256, 256, 0, stream>>>(feat + (OFFIN), xx, (CIN));                \
    if(fullND){                                                                             \
      gram_sym3_k<CIN><<<dim3(136, 1, 8), 256, 0, stream>>>(feat + (OFFIN), xx, nd, 0);     \
      topk_f<<<Bb * Nn / 4, 256, 0, stream>>>(nd, idxb, 0);                                 \
    } else {                                                                                \
      for(int bb = 0; bb < Bb; bb++){                                                       \
        gram_sym3_k<CIN><<<dim3(136, 1, 1), 256, 0, stream>>>(feat + (OFFIN), xx, nd, bb);  \
        topk_f<<<Nn / 4, 256, 0, stream>>>(nd, idxb, bb * Nn);                              \
      }                                                                                     \
    }

  // ---------------- Layer 1
  RUN_KNN(64, 0)
  wt_prep_k<<<(64 * 64 + 255) / 256, 256, 0, stream>>>(Wl[1], Wt1, Wt2, 64, 64);
  gemm_ab_k<64, 64><<<Bb * Nn / 16, 256, 0, stream>>>(feat + 0, FC, Wt1, Wt2, Abuf, Bbuf);
  edge_reduce_k<64><<<Bb * Nn / 64, 256, 0, stream>>>(Abuf, Bbuf, idxb, feat + 64, Mn, psum, psq);
  bn_finalize2_k<<<64, 64, 0, stream>>>(psum, psq, Gl[1], Bl[1], scal, shft, 64, Bb * Nn / 64);
  bn_apply_k<<<(Bb * Nn * 64) / 256, 256, 0, stream>>>(feat + 64, Mn, scal, shft, Gl[1], 64);

  // ---------------- Layer 2
  RUN_KNN(64, 64)
  wt_prep_k<<<(64 * 128 + 255) / 256, 256, 0, stream>>>(Wl[2], Wt1, Wt2, 64, 128);
  gemm_ab_k<64, 128><<<Bb * Nn / 16, 256, 0, stream>>>(feat + 64, FC, Wt1, Wt2, Abuf, Bbuf);
  edge_reduce_k<128><<<Bb * Nn / 32, 256, 0, stream>>>(Abuf, Bbuf, idxb, feat + 128, Mn, psum, psq);
  bn_finalize2_k<<<128, 64, 0, stream>>>(psum, psq, Gl[2], Bl[2], scal, shft, 128, Bb * Nn / 32);
  bn_apply_k<<<(Bb * Nn * 128) / 256, 256, 0, stream>>>(feat + 128, Mn, scal, shft, Gl[2], 128);

  // ---------------- Layer 3
  RUN_KNN(128, 128)
  wt_prep_k<<<(128 * 256 + 255) / 256, 256, 0, stream>>>(Wl[3], Wt1, Wt2, 128, 256);
  gemm_ab_k<128, 256><<<Bb * Nn / 16, 256, 0, stream>>>(feat + 128, FC, Wt1, Wt2, Abuf, Bbuf);
  edge_reduce_k<256><<<Bb * Nn / 16, 256, 0, stream>>>(Abuf, Bbuf, idxb, feat + 256, Mn, psum, psq);
  bn_finalize2_k<<<256, 64, 0, stream>>>(psum, psq, Gl[3], Bl[3], scal, shft, 256, Bb * Nn / 16);
  bn_apply_k<<<(Bb * Nn * 256) / 256, 256, 0, stream>>>(feat + 256, Mn, scal, shft, Gl[3], 256);

  // ---------------- Final 1x1 conv (split-bf16 MFMA) + global max pool
  cvt_k<<<(Bb * Nn * FC / 4 + 255) / 256, 256, 0, stream>>>(feat, featH, featL, Bb * Nn * FC / 4);
  cvt_k<<<(1024 * 512 / 4 + 255) / 256, 256, 0, stream>>>(wf, wfH, wfL, 1024 * 512 / 4);
  fc3_k<<<dim3(8, 128), 256, 0, stream>>>(featH, featL, wfH, wfL, pmax);
  fc_reduce_k<<<(Bb * 1024 + 255) / 256, 256, 0, stream>>>(pmax, bf, out);
  #undef RUN_KNN
}

// Round 12
// 599.449 us; speedup vs baseline: 3.0630x; 1.0097x over previous
//
#include <hip/hip_runtime.h>
#include <cstdint>

#define Bb 8
#define Nn 2048
#define Kk 20
#define FC 512
#define EPSc 1e-5f
#define SLOPEc 0.2f

#define TS 128
#define KP 32
#define LDT2 36

typedef __attribute__((ext_vector_type(8))) short short8v;
typedef __attribute__((ext_vector_type(4))) float f32x4;

static __device__ __forceinline__ float leaky(float y){ return y >= 0.f ? y : SLOPEc * y; }

static __device__ __forceinline__ ushort f2bf(float x){
  uint u = __float_as_uint(x);
  return (ushort)((u + 0x7fffu + ((u >> 16) & 1u)) >> 16);
}
static __device__ __forceinline__ float bf2f(ushort b){
  return __uint_as_float(((uint)b) << 16);
}

// ---------------- Wt prep: Wt1[c][o] = W[o][c]; Wt2[c][o] = W[o][C+c]-W[o][c]
__global__ void wt_prep_k(const float* __restrict__ W, float* __restrict__ Wt1,
                          float* __restrict__ Wt2, int C, int O){
  int i = blockIdx.x * 256 + threadIdx.x;
  if(i >= C * O) return;
  int c = i / O, o = i - c * O;
  float w1 = W[o * 2 * C + c];
  float w2 = W[o * 2 * C + C + c];
  Wt1[c * O + o] = w1;
  Wt2[c * O + o] = w2 - w1;
}

// ---------------- A = h·W1^T ; Bc = h·(W2-W1)^T   (16 rows per block)
template<int C, int O>
__global__ __launch_bounds__(256) void gemm_ab_k(const float* __restrict__ h, int hstride,
                    const float* __restrict__ Wt1, const float* __restrict__ Wt2,
                    float* __restrict__ A, float* __restrict__ Bc){
  constexpr int NG = 256 / O;
  constexpr int ROWS = 16;
  constexpr int RPG = ROWS / NG;
  __shared__ float xs[ROWS][C];
  int t = threadIdx.x;
  int row0 = blockIdx.x * ROWS;
  for(int i = t; i < ROWS * C; i += 256){
    int r = i / C, c = i - r * C;
    xs[r][c] = h[(size_t)(row0 + r) * hstride + c];
  }
  __syncthreads();
  int o = t % O, g = t / O;
  float accA[RPG], accB[RPG];
  #pragma unroll
  for(int r = 0; r < RPG; r++){ accA[r] = 0.f; accB[r] = 0.f; }
  for(int c = 0; c < C; c++){
    float wa = Wt1[c * O + o], wb = Wt2[c * O + o];
    #pragma unroll
    for(int r = 0; r < RPG; r++){
      float x = xs[g * RPG + r][c];
      accA[r] = fmaf(x, wa, accA[r]);
      accB[r] = fmaf(x, wb, accB[r]);
    }
  }
  for(int r = 0; r < RPG; r++){
    size_t id = (size_t)(row0 + g * RPG + r) * O + o;
    A[id] = accA[r];
    Bc[id] = accB[r];
  }
}

// ---------------- gather + k-reduce (max/min) + DETERMINISTIC BN partials
template<int O>
__global__ __launch_bounds__(256) void edge_reduce_k(const float* __restrict__ A,
                       const float* __restrict__ Bc, const int* __restrict__ idx,
                       float* __restrict__ outMax, float* __restrict__ outMin,
                       float* __restrict__ psum, float* __restrict__ psq){
  constexpr int NG = 256 / O;
  constexpr int RPG = 16;
  constexpr int ROWS = NG * RPG;
  int t = threadIdx.x;
  int o = t % O, g = t / O;
  int blocks_per_b = Nn / ROWS;
  int b = blockIdx.x / blocks_per_b;
  int n0 = (blockIdx.x % blocks_per_b) * ROWS;
  float tsum = 0.f, tsq = 0.f;
  for(int r = 0; r < RPG; r++){
    int n = n0 + g * RPG + r;
    size_t rowid = (size_t)b * Nn + n;
    const int* ip = idx + rowid * Kk;
    float bv = Bc[rowid * O + o];
    float amax = -3.4e38f, amin = 3.4e38f, asum = 0.f, asq = 0.f;
    for(int k = 0; k < Kk; k++){
      int nb = ip[k];
      float a = A[((size_t)b * Nn + nb) * O + o];
      amax = fmaxf(amax, a);
      amin = fminf(amin, a);
      asum += a;
      asq = fmaf(a, a, asq);
    }
    outMax[rowid * FC + o] = amax + bv;
    outMin[rowid * O + o]  = amin + bv;
    tsum += asum + (float)Kk * bv;
    tsq  += asq + 2.f * bv * asum + (float)Kk * bv * bv;
  }
  __shared__ float red[256];
  red[t] = tsum; __syncthreads();
  if(g == 0){
    float s = 0.f;
    for(int gg = 0; gg < NG; gg++) s += red[gg * O + o];
    psum[(size_t)blockIdx.x * O + o] = s;
  }
  __syncthreads();
  red[t] = tsq; __syncthreads();
  if(g == 0){
    float s = 0.f;
    for(int gg = 0; gg < NG; gg++) s += red[gg * O + o];
    psq[(size_t)blockIdx.x * O + o] = s;
  }
}

// ---------------- deterministic BN finalize: one wave per channel
__global__ __launch_bounds__(64) void bn_finalize2_k(const float* __restrict__ psum,
                              const float* __restrict__ psq,
                              const float* __restrict__ gam, const float* __restrict__ bet,
                              float* __restrict__ scale, float* __restrict__ shift,
                              int O, int nb){
  int o = blockIdx.x;
  int t = threadIdx.x;
  float s = 0.f, q = 0.f;
  for(int bk = t; bk < nb; bk += 64){
    s += psum[(size_t)bk * O + o];
    q += psq[(size_t)bk * O + o];
  }
  #pragma unroll
  for(int off2 = 1; off2 < 64; off2 <<= 1){
    s += __shfl_xor(s, off2, 64);
    q += __shfl_xor(q, off2, 64);
  }
  if(t == 0){
    float cnt = (float)Bb * (float)Nn * (float)Kk;
    float mean = s / cnt;
    float var = q / cnt - mean * mean;
    var = fmaxf(var, 0.f);
    float sc = gam[o] * rsqrtf(var + EPSc);
    scale[o] = sc;
    shift[o] = bet[o] - mean * sc;
  }
}

__global__ void bn_apply_k(float* __restrict__ featsl, const float* __restrict__ Mn,
                           const float* __restrict__ scale, const float* __restrict__ shift,
                           const float* __restrict__ gam, int O){
  int i = blockIdx.x * 256 + threadIdx.x;
  if(i >= Bb * Nn * O) return;
  int o = i % O;
  size_t row = (size_t)(i / O);
  float v = (gam[o] >= 0.f) ? featsl[row * FC + o] : Mn[row * O + o];
  float y = fmaf(scale[o], v, shift[o]);
  featsl[row * FC + o] = leaky(y);
}

// ---------------- row squared norms
__global__ void rownorm_k(const float* __restrict__ featsl, float* __restrict__ xx, int C){
  int i = blockIdx.x * 256 + threadIdx.x;
  if(i >= Bb * Nn) return;
  const float* p = featsl + (size_t)i * FC;
  float s = 0.f;
  for(int c = 0; c < C; c++) s = fmaf(p[c], p[c], s);
  xx[i] = s;
}

// ---------------- symmetric neg_dist, upper-triangle 128x128 tiles (verified
// bit-exact mirror: absmax stable 0.15625 across R10/R11). FROZEN.
template<int CIN>
__global__ __launch_bounds__(256) void gram_sym3_k(const float* __restrict__ feat,
                     const float* __restrict__ xx, float* __restrict__ nd, int b0){
  int b = b0 + blockIdx.z;
  float* ndb = nd + (size_t)blockIdx.z * Nn * Nn;
  int id = blockIdx.x;
  int iB = 0;
  while(id >= 16 - iB){ id -= 16 - iB; iB++; }
  int jB = iB + id;
  int n0 = iB * TS, m0 = jB * TS;
  __shared__ float smem[2 * TS * LDT2];
  float* fa = smem;
  float* fb = smem + TS * LDT2;
  float* LT = smem;
  int t = threadIdx.x, tx = t & 15, ty = t >> 4;
  float acc[8][8] = {};
  const float* Abase = feat + ((size_t)b * Nn + n0) * FC;
  const float* Bbase = feat + ((size_t)b * Nn + m0) * FC;
  for(int c0 = 0; c0 < CIN; c0 += KP){
    #pragma unroll
    for(int p = 0; p < 4; p++){
      int f = t + p * 256;
      int n = f >> 3, c4 = (f & 7) << 2;
      float4 va = *(const float4*)(Abase + (size_t)n * FC + c0 + c4);
      float4 vb = *(const float4*)(Bbase + (size_t)n * FC + c0 + c4);
      *(float4*)&fa[n * LDT2 + c4] = va;
      *(float4*)&fb[n * LDT2 + c4] = vb;
    }
    __syncthreads();
    #pragma unroll
    for(int c4 = 0; c4 < KP; c4 += 4){
      float4 a4[8];
      #pragma unroll
      for(int i = 0; i < 8; i++) a4[i] = *(const float4*)&fa[(ty + 16 * i) * LDT2 + c4];
      #pragma unroll
      for(int j = 0; j < 8; j++){
        float4 b4 = *(const float4*)&fb[(tx + 16 * j) * LDT2 + c4];
        #pragma unroll
        for(int i = 0; i < 8; i++) acc[i][j] = fmaf(a4[i].x, b4.x, acc[i][j]);
        #pragma unroll
        for(int i = 0; i < 8; i++) acc[i][j] = fmaf(a4[i].y, b4.y, acc[i][j]);
        #pragma unroll
        for(int i = 0; i < 8; i++) acc[i][j] = fmaf(a4[i].z, b4.z, acc[i][j]);
        #pragma unroll
        for(int i = 0; i < 8; i++) acc[i][j] = fmaf(a4[i].w, b4.w, acc[i][j]);
      }
    }
    __syncthreads();
  }
  float xn[8], xm[8];
  #pragma unroll
  for(int i = 0; i < 8; i++) xn[i] = xx[(size_t)b * Nn + n0 + ty + 16 * i];
  #pragma unroll
  for(int j = 0; j < 8; j++) xm[j] = xx[(size_t)b * Nn + m0 + tx + 16 * j];
  #pragma unroll
  for(int i = 0; i < 8; i++){
    size_t rbase = (size_t)(n0 + ty + 16 * i) * Nn + m0;
    #pragma unroll
    for(int j = 0; j < 8; j++)
      ndb[rbase + tx + 16 * j] = 2.f * acc[i][j] - xn[i] - xm[j];
  }
  if(iB != jB){
    #pragma unroll
    for(int h = 0; h < 2; h++){
      __syncthreads();
      #pragma unroll
      for(int jj = 0; jj < 4; jj++){
        int j = h * 4 + jj;
        int c = tx + 16 * jj;
        #pragma unroll
        for(int i = 0; i < 8; i++){
          int r = ty + 16 * i;
          LT[c * 132 + r] = 2.f * acc[i][j] - xm[j] - xn[i];
        }
      }
      __syncthreads();
      int c2 = t >> 2;
      int rq = t & 3;
      size_t gr = (size_t)(m0 + 64 * h + c2) * Nn + n0;
      #pragma unroll
      for(int q = 0; q < 8; q++){
        int r4 = rq * 4 + q * 16;
        float4 v = *(const float4*)&LT[c2 * 132 + r4];
        *(float4*)&ndb[gr + r4] = v;
      }
    }
  }
}

// ---------------- top-K: threshold prefilter + exact bitonic on candidates.
// float4 loads (R12): partition of values across lanes changed, but the output
// is partition-independent: T only defines the candidate set (always contains
// the top-20 since >=20 values >= T), and the final bitonic ranks exact
// (orderable_value, ~idx) keys == lax.top_k semantics. Comparison-only.
__global__ __launch_bounds__(256) void topk_f(const float* __restrict__ nd,
                                              int* __restrict__ idxout, int rowbase){
  int wid = threadIdx.x >> 6, lane = threadIdx.x & 63;
  int row = blockIdx.x * 4 + wid;
  const float* src = nd + (size_t)row * Nn;
  __shared__ unsigned long long keys[4][64];
  unsigned long long* wkeys = keys[wid];
  float4 x4[8];
  #pragma unroll
  for(int j = 0; j < 8; j++) x4[j] = *(const float4*)&src[j * 256 + lane * 4];
  // per-lane max (order-independent: fmax is assoc/comm on finite values)
  float M = -3.4e38f;
  #pragma unroll
  for(int j = 0; j < 8; j++)
    M = fmaxf(M, fmaxf(fmaxf(x4[j].x, x4[j].y), fmaxf(x4[j].z, x4[j].w)));
  // bitonic sort (ascending) of the 64 lane maxes
  float v = M;
  #pragma unroll
  for(int k = 2; k <= 64; k <<= 1){
    #pragma unroll
    for(int j2 = k >> 1; j2 > 0; j2 >>= 1){
      float o = __shfl_xor(v, j2, 64);
      bool takeMin = (((lane & k) == 0) == ((lane & j2) == 0));
      v = takeMin ? fminf(v, o) : fmaxf(v, o);
    }
  }
  float T = __shfl(v, 44, 64);        // 20th largest lane max
  // ballot-compaction of candidates (deterministic, no atomics)
  unsigned long long lmlt = (1ull << lane) - 1ull;
  int cnt = 0;
  #pragma unroll
  for(int j = 0; j < 8; j++){
    float vv[4] = {x4[j].x, x4[j].y, x4[j].z, x4[j].w};
    #pragma unroll
    for(int q = 0; q < 4; q++){
      bool pred = vv[q] >= T;
      unsigned long long mk = __ballot(pred);
      if(pred){
        int pos = cnt + (int)__popcll(mk & lmlt);
        if(pos < 64){
          unsigned int bb = __float_as_uint(vv[q]);
          unsigned int ord = (bb & 0x80000000u) ? ~bb : (bb | 0x80000000u);
          wkeys[pos] = ((unsigned long long)ord << 32) | (unsigned int)~(j * 256 + lane * 4 + q);
        }
      }
      cnt += (int)__popcll(mk);
    }
  }
  __syncthreads();
  if(cnt <= 64){
    unsigned long long key = (lane < cnt) ? wkeys[lane] : 0ull;
    #pragma unroll
    for(int k = 2; k <= 64; k <<= 1){
      #pragma unroll
      for(int j2 = k >> 1; j2 > 0; j2 >>= 1){
        unsigned long long o = __shfl_xor(key, j2, 64);
        bool takeMin = (((lane & k) == 0) == ((lane & j2) == 0));
        bool less = key < o;
        key = (takeMin == less) ? key : o;
      }
    }
    if(lane >= 44)
      idxout[((size_t)(rowbase + row)) * Kk + (63 - lane)] = (int)~(unsigned int)key;
  } else {
    // fallback: exact 20-pass serial selection on x4 (lowest-index tie-break)
    int sel = 0;
    for(int s = 0; s < Kk; s++){
      float m = -3.4e38f;
      #pragma unroll
      for(int j = 0; j < 8; j++)
        m = fmaxf(m, fmaxf(fmaxf(x4[j].x, x4[j].y), fmaxf(x4[j].z, x4[j].w)));
      #pragma unroll
      for(int off = 1; off < 64; off <<= 1) m = fmaxf(m, __shfl_xor(m, off, 64));
      int bi = 0x7fffffff;
      #pragma unroll
      for(int j = 7; j >= 0; j--){
        float vv[4] = {x4[j].x, x4[j].y, x4[j].z, x4[j].w};
        #pragma unroll
        for(int q = 3; q >= 0; q--)
          bi = (vv[q] == m) ? (j * 256 + lane * 4 + q) : bi;
      }
      #pragma unroll
      for(int off = 1; off < 64; off <<= 1){ int ob = __shfl_xor(bi, off, 64); bi = min(bi, ob); }
      if(lane == s) sel = bi;
      #pragma unroll
      for(int j = 0; j < 8; j++){
        int base = j * 256 + lane * 4;
        if(bi == base + 0) x4[j].x = -3.4e38f;
        if(bi == base + 1) x4[j].y = -3.4e38f;
        if(bi == base + 2) x4[j].z = -3.4e38f;
        if(bi == base + 3) x4[j].w = -3.4e38f;
      }
    }
    if(lane < Kk) idxout[((size_t)(rowbase + row)) * Kk + lane] = sel;
  }
}

// ---------------- f32 -> (hi,lo) bf16 split for BOTH feat and wf (one launch)
__global__ void cvt2_k(const float* __restrict__ feat, ushort* __restrict__ fH,
                       ushort* __restrict__ fL, const float* __restrict__ wf,
                       ushort* __restrict__ wH, ushort* __restrict__ wL,
                       int nfeat4, int nwf4){
  int i = blockIdx.x * 256 + threadIdx.x;
  const float* in; ushort* ho; ushort* lo2; int k;
  if(i < nfeat4){ in = feat; ho = fH; lo2 = fL; k = i; }
  else { int j = i - nfeat4; if(j >= nwf4) return; in = wf; ho = wH; lo2 = wL; k = j; }
  float4 v = *(const float4*)(in + (size_t)k * 4);
  float vv[4] = {v.x, v.y, v.z, v.w};
  ushort h[4], l[4];
  #pragma unroll
  for(int j = 0; j < 4; j++){
    h[j] = f2bf(vv[j]);
    float r = vv[j] - bf2f(h[j]);
    l[j] = f2bf(r);
  }
  ushort4 uh, ul;
  uh.x = h[0]; uh.y = h[1]; uh.z = h[2]; uh.w = h[3];
  ul.x = l[0]; ul.y = l[1]; ul.z = l[2]; ul.w = l[3];
  ((ushort4*)ho)[k] = uh;
  ((ushort4*)lo2)[k] = ul;
}

// ---------------- final conv via split-bf16 MFMA + fused col-max
#define LDH 40
__global__ __launch_bounds__(256) void fc3_k(const ushort* __restrict__ fH, const ushort* __restrict__ fL,
        const ushort* __restrict__ wH, const ushort* __restrict__ wL,
        float* __restrict__ pmax){
  __shared__ ushort aH[128 * LDH], aL[128 * LDH], bH[128 * LDH], bL[128 * LDH];
  __shared__ float red[2][128];
  int t = threadIdx.x;
  int lane = t & 63, wid = t >> 6;
  int wm = wid >> 1, wn = wid & 1;
  int rt = blockIdx.y, o0 = blockIdx.x * 128;
  const ushort* gaH = fH + (size_t)rt * 128 * 512;
  const ushort* gaL = fL + (size_t)rt * 128 * 512;
  const ushort* gbH = wH + (size_t)o0 * 512;
  const ushort* gbL = wL + (size_t)o0 * 512;
  f32x4 acc[4][4];
  #pragma unroll
  for(int i = 0; i < 4; i++)
    #pragma unroll
    for(int j = 0; j < 4; j++)
      acc[i][j] = (f32x4){0.f, 0.f, 0.f, 0.f};
  for(int c0 = 0; c0 < 512; c0 += 32){
    #pragma unroll
    for(int p = 0; p < 2; p++){
      int r = (t >> 2) + p * 64, s = (t & 3) * 8;
      size_t go = (size_t)r * 512 + c0 + s;
      int lof = r * LDH + s;
      *(uint4*)&aH[lof] = *(const uint4*)&gaH[go];
      *(uint4*)&aL[lof] = *(const uint4*)&gaL[go];
      *(uint4*)&bH[lof] = *(const uint4*)&gbH[go];
      *(uint4*)&bL[lof] = *(const uint4*)&gbL[go];
    }
    __syncthreads();
    int koff = (lane >> 4) * 8;
    short8v AH[4], AL[4], BH[4], BL[4];
    #pragma unroll
    for(int f = 0; f < 4; f++){
      int ra = (wm * 64 + f * 16 + (lane & 15)) * LDH + koff;
      AH[f] = *(const short8v*)&aH[ra];
      AL[f] = *(const short8v*)&aL[ra];
      int rb = (wn * 64 + f * 16 + (lane & 15)) * LDH + koff;
      BH[f] = *(const short8v*)&bH[rb];
      BL[f] = *(const short8v*)&bL[rb];
    }
    #pragma unroll
    for(int i = 0; i < 4; i++)
      #pragma unroll
      for(int j = 0; j < 4; j++){
        acc[i][j] = __builtin_amdgcn_mfma_f32_16x16x32_bf16(AH[i], BH[j], acc[i][j], 0, 0, 0);
        acc[i][j] = __builtin_amdgcn_mfma_f32_16x16x32_bf16(AH[i], BL[j], acc[i][j], 0, 0, 0);
        acc[i][j] = __builtin_amdgcn_mfma_f32_16x16x32_bf16(AL[i], BH[j], acc[i][j], 0, 0, 0);
      }
    __syncthreads();
  }
  #pragma unroll
  for(int j = 0; j < 4; j++){
    float m = -3.4e38f;
    #pragma unroll
    for(int i = 0; i < 4; i++)
      m = fmaxf(m, fmaxf(fmaxf(acc[i][j][0], acc[i][j][1]), fmaxf(acc[i][j][2], acc[i][j][3])));
    m = fmaxf(m, __shfl_xor(m, 16, 64));
    m = fmaxf(m, __shfl_xor(m, 32, 64));
    if(lane < 16) red[wm][wn * 64 + j * 16 + lane] = m;
  }
  __syncthreads();
  if(t < 128)
    pmax[(size_t)rt * 1024 + o0 + t] = fmaxf(red[0][t], red[1][t]);
}

__global__ void fc_reduce_k(const float* __restrict__ pmax, const float* __restrict__ bf,
                            float* __restrict__ out){
  int i = blockIdx.x * 256 + threadIdx.x;
  if(i >= Bb * 1024) return;
  int b = i >> 10, o = i & 1023;
  float m = -3.4e38f;
  for(int rt = b * 16; rt < b * 16 + 16; rt++) m = fmaxf(m, pmax[(size_t)rt * 1024 + o]);
  out[i] = m + bf[o];
}

// =====================================================================
extern "C" void kernel_launch(void* const* d_in, const int* in_sizes, int n_in,
                              void* d_out, int out_size, void* d_ws, size_t ws_size,
                              hipStream_t stream){
  const float* x  = (const float*)d_in[0];
  const int* idx0 = (const int*)d_in[1];
  const float* Wl[4] = {(const float*)d_in[2], (const float*)d_in[5], (const float*)d_in[8],  (const float*)d_in[11]};
  const float* Gl[4] = {(const float*)d_in[3], (const float*)d_in[6], (const float*)d_in[9],  (const float*)d_in[12]};
  const float* Bl[4] = {(const float*)d_in[4], (const float*)d_in[7], (const float*)d_in[10], (const float*)d_in[13]};
  const float* wf = (const float*)d_in[14];
  const float* bf = (const float*)d_in[15];
  float* out = (float*)d_out;

  char* base = (char*)d_ws;
  size_t off = 0;
  auto alloc = [&](size_t bytes) -> char* {
    char* p = base + off;
    off += (bytes + 255) & ~(size_t)255;
    return p;
  };
  float* feat = (float*)alloc((size_t)Bb * Nn * FC * 4);
  float* Abuf = (float*)alloc((size_t)Bb * Nn * 256 * 4);
  float* Bbuf = (float*)alloc((size_t)Bb * Nn * 256 * 4);
  float* Mn   = (float*)alloc((size_t)Bb * Nn * 256 * 4);
  int*   idxb = (int*)  alloc((size_t)Bb * Nn * Kk * 4);
  float* xx   = (float*)alloc((size_t)Bb * Nn * 4);
  float* Wt1  = (float*)alloc(128 * 256 * 4);
  float* Wt2  = (float*)alloc(128 * 256 * 4);
  float* psum = (float*)alloc((size_t)1024 * 256 * 4);
  float* psq  = (float*)alloc((size_t)1024 * 256 * 4);
  float* scal = (float*)alloc(256 * 4);
  float* shft = (float*)alloc(256 * 4);
  float* pmax = (float*)alloc((size_t)128 * 1024 * 4);
  float* nd   = (float*)(base + off);
  bool fullND = (off + (size_t)Bb * Nn * Nn * 4) <= ws_size;

  ushort* featH = (ushort*)Abuf;
  ushort* featL = (ushort*)Bbuf;
  ushort* wfH   = (ushort*)Mn;
  ushort* wfL   = ((ushort*)Mn) + (size_t)1024 * 512;

  // ---------------- Layer 0 (given indices, C=3, O=64, out at feat+0)
  wt_prep_k<<<(3 * 64 + 255) / 256, 256, 0, stream>>>(Wl[0], Wt1, Wt2, 3, 64);
  gemm_ab_k<3, 64><<<Bb * Nn / 16, 256, 0, stream>>>(x, 3, Wt1, Wt2, Abuf, Bbuf);
  edge_reduce_k<64><<<Bb * Nn / 64, 256, 0, stream>>>(Abuf, Bbuf, idx0, feat + 0, Mn, psum, psq);
  bn_finalize2_k<<<64, 64, 0, stream>>>(psum, psq, Gl[0], Bl[0], scal, shft, 64, Bb * Nn / 64);
  bn_apply_k<<<(Bb * Nn * 64) / 256, 256, 0, stream>>>(feat + 0, Mn, scal, shft, Gl[0], 64);

  #define RUN_KNN(CIN, OFFIN)                                                               \
    rownorm_k<<<Bb * Nn / 256, 256, 0, stream>>>(feat + (OFFIN), xx, (CIN));                \
    if(fullND){                                                                             \
      gram_sym3_k<CIN><<<dim3(136, 1, 8), 256, 0, stream>>>(feat + (OFFIN), xx, nd, 0);     \
      topk_f<<<Bb * Nn / 4, 256, 0, stream>>>(nd, idxb, 0);                                 \
    } else {                                                                                \
      for(int bb = 0; bb < Bb; bb++){                                                       \
        gram_sym3_k<CIN><<<dim3(136, 1, 1), 256, 0, stream>>>(feat + (OFFIN), xx, nd, bb);  \
        topk_f<<<Nn / 4, 256, 0, stream>>>(nd, idxb, bb * Nn);                              \
      }                                                                                     \
    }

  // ---------------- Layer 1
  RUN_KNN(64, 0)
  wt_prep_k<<<(64 * 64 + 255) / 256, 256, 0, stream>>>(Wl[1], Wt1, Wt2, 64, 64);
  gemm_ab_k<64, 64><<<Bb * Nn / 16, 256, 0, stream>>>(feat + 0, FC, Wt1, Wt2, Abuf, Bbuf);
  edge_reduce_k<64><<<Bb * Nn / 64, 256, 0, stream>>>(Abuf, Bbuf, idxb, feat + 64, Mn, psum, psq);
  bn_finalize2_k<<<64, 64, 0, stream>>>(psum, psq, Gl[1], Bl[1], scal, shft, 64, Bb * Nn / 64);
  bn_apply_k<<<(Bb * Nn * 64) / 256, 256, 0, stream>>>(feat + 64, Mn, scal, shft, Gl[1], 64);

  // ---------------- Layer 2
  RUN_KNN(64, 64)
  wt_prep_k<<<(64 * 128 + 255) / 256, 256, 0, stream>>>(Wl[2], Wt1, Wt2, 64, 128);
  gemm_ab_k<64, 128><<<Bb * Nn / 16, 256, 0, stream>>>(feat + 64, FC, Wt1, Wt2, Abuf, Bbuf);
  edge_reduce_k<128><<<Bb * Nn / 32, 256, 0, stream>>>(Abuf, Bbuf, idxb, feat + 128, Mn, psum, psq);
  bn_finalize2_k<<<128, 64, 0, stream>>>(psum, psq, Gl[2], Bl[2], scal, shft, 128, Bb * Nn / 32);
  bn_apply_k<<<(Bb * Nn * 128) / 256, 256, 0, stream>>>(feat + 128, Mn, scal, shft, Gl[2], 128);

  // ---------------- Layer 3
  RUN_KNN(128, 128)
  wt_prep_k<<<(128 * 256 + 255) / 256, 256, 0, stream>>>(Wl[3], Wt1, Wt2, 128, 256);
  gemm_ab_k<128, 256><<<Bb * Nn / 16, 256, 0, stream>>>(feat + 128, FC, Wt1, Wt2, Abuf, Bbuf);
  edge_reduce_k<256><<<Bb * Nn / 16, 256, 0, stream>>>(Abuf, Bbuf, idxb, feat + 256, Mn, psum, psq);
  bn_finalize2_k<<<256, 64, 0, stream>>>(psum, psq, Gl[3], Bl[3], scal, shft, 256, Bb * Nn / 16);
  bn_apply_k<<<(Bb * Nn * 256) / 256, 256, 0, stream>>>(feat + 256, Mn, scal, shft, Gl[3], 256);

  // ---------------- Final 1x1 conv (split-bf16 MFMA) + global max pool
  {
    int nfeat4 = Bb * Nn * FC / 4;
    int nwf4 = 1024 * 512 / 4;
    cvt2_k<<<(nfeat4 + nwf4 + 255) / 256, 256, 0, stream>>>(feat, featH, featL, wf, wfH, wfL, nfeat4, nwf4);
  }
  fc3_k<<<dim3(8, 128), 256, 0, stream>>>(featH, featL, wfH, wfL, pmax);
  fc_reduce_k<<<(Bb * 1024 + 255) / 256, 256, 0, stream>>>(pmax, bf, out);
  #undef RUN_KNN
}